// Round 2
// baseline (3677.843 us; speedup 1.0000x reference)
//
#include <hip/hip_runtime.h>
#include <hip/hip_bf16.h>
#include <math.h>

#define HDIM 768
#define NSTATE 16

// ---------------------------------------------------------------------------
// Encoder: u0[b,j,l] = (softsign(x_raw @ W1 + b1) @ W2 + b2)[b,l,j]
// Fuses the tiny K=8 first GEMM into the A-tile staging of the second GEMM.
// Writes output directly in (B,H,L) "u" layout.
// ---------------------------------------------------------------------------
__global__ void __launch_bounds__(256) enc_kernel(
    const float* __restrict__ xraw,   // (B*2048, 8)
    const float* __restrict__ w1,     // (8, 768)
    const float* __restrict__ b1,     // (768)
    const float* __restrict__ w2,     // (768, 768)
    const float* __restrict__ b2,     // (768)
    float* __restrict__ u0)           // (B, 768, 2048)
{
    __shared__ __align__(16) float xs[8][65];     // [q][row]
    __shared__ __align__(16) float hs[64][68];    // [kk][row]
    __shared__ __align__(16) float ws2[64][68];   // [kk][jj]
    int tid = threadIdx.x;
    int r0 = blockIdx.x * 64;          // row tile (b*2048 + l)
    int j0 = blockIdx.y * 64;          // output-channel tile
    int b  = r0 >> 11;
    int l0 = r0 & 2047;
    int tl = tid & 15, td = tid >> 4;

    for (int p = tid; p < 512; p += 256) {
        xs[p & 7][p >> 3] = xraw[(size_t)r0 * 8 + p];
    }
    __syncthreads();

    float acc[4][4] = {};
    for (int k0 = 0; k0 < HDIM; k0 += 64) {
        for (int p = tid; p < 4096; p += 256) {
            int rr = p & 63, kk = p >> 6;
            float hv = b1[k0 + kk];
#pragma unroll
            for (int q = 0; q < 8; ++q)
                hv = fmaf(xs[q][rr], w1[q * HDIM + k0 + kk], hv);
            hv = hv / (1.0f + fabsf(hv));
            hs[kk][rr] = hv;
        }
        for (int p = tid; p < 4096; p += 256) {
            int jj = p & 63, kk = p >> 6;
            ws2[kk][jj] = w2[(size_t)(k0 + kk) * HDIM + j0 + jj];
        }
        __syncthreads();
#pragma unroll 8
        for (int kk = 0; kk < 64; ++kk) {
            float4 hv = *(const float4*)&hs[kk][tl * 4];
            float hh[4] = {hv.x, hv.y, hv.z, hv.w};
#pragma unroll
            for (int i = 0; i < 4; ++i) {
                float wv = ws2[kk][td * 4 + i];
#pragma unroll
                for (int j = 0; j < 4; ++j)
                    acc[i][j] = fmaf(wv, hh[j], acc[i][j]);
            }
        }
        __syncthreads();
    }
#pragma unroll
    for (int i = 0; i < 4; ++i) {
        int j = j0 + td * 4 + i;
        float bb = b2[j];
        float4 ov;
        ov.x = acc[i][0] + bb; ov.y = acc[i][1] + bb;
        ov.z = acc[i][2] + bb; ov.w = acc[i][3] + bb;
        *(float4*)&u0[((size_t)b * HDIM + j) * 2048 + l0 + tl * 4] = ov;
    }
}

// ---------------------------------------------------------------------------
// SSM: per (b,h) row, bidirectional 16-state complex recurrence.
// One wave handles 2 rows (lanes 0-31 row gh0, 32-63 row gh1).
// Within 32 lanes: lanes 0-15 forward (dir 0), 16-31 backward (dir 1).
// y accumulated in LDS; epilogue applies +D*u, exact GELU, downsample, store.
// ---------------------------------------------------------------------------
__global__ void __launch_bounds__(64) ssm_kernel(
    const float* __restrict__ u,       // (B, H, L)
    float* __restrict__ y,             // (B, H, L/ds) output (gelu'd)
    const float* __restrict__ log_dt,  // (H)
    const float* __restrict__ log_A_real, // (H, N)
    const float* __restrict__ A_imag,  // (H, N)
    const float* __restrict__ C_ri,    // (2, H, N, 2)
    const float* __restrict__ Dp,      // (H)
    int L, int ds)
{
    extern __shared__ float ybuf[];    // 2 * L floats
    int lane = threadIdx.x;
    int half = lane >> 5;
    int sub  = lane & 31;
    int dir  = (sub >> 4) & 1;
    int n    = sub & 15;
    int gh   = blockIdx.x * 2 + half;  // == b*H + h
    int h    = gh % HDIM;

    // discretize: z = exp(dt*A), w = 2*C*(z-1)/A
    float dt  = expf(log_dt[h]);
    float Ar  = -expf(log_A_real[h * NSTATE + n]);
    float Ai  = A_imag[h * NSTATE + n];
    float er  = expf(dt * Ar);
    float th  = dt * Ai;
    float zr  = er * cosf(th), zi = er * sinf(th);
    float den = Ar * Ar + Ai * Ai;
    float t0  = zr - 1.0f;
    float dBr = (t0 * Ar + zi * Ai) / den;
    float dBi = (zi * Ar - t0 * Ai) / den;
    float Cr  = C_ri[((dir * HDIM + h) * NSTATE + n) * 2 + 0];
    float Ci  = C_ri[((dir * HDIM + h) * NSTATE + n) * 2 + 1];
    float wr  = 2.0f * (Cr * dBr - Ci * dBi);
    float wi  = 2.0f * (Cr * dBi + Ci * dBr);

    const float* ur = u + (size_t)gh * L;
    float* yb = ybuf + half * L;
    int Lh = L >> 1;

    float sr, si;
    {   // k = 0 peeled: fwd s = u[0]; bwd t = 0
        float u0v = ur[0];
        sr = dir ? 0.0f : u0v;
        si = 0.0f;
        float c = wr * sr;
#pragma unroll
        for (int m = 1; m < 16; m <<= 1) c += __shfl_xor(c, m, 64);
        if (n == 0) yb[dir ? (L - 1) : 0] = c;
    }
#pragma unroll 4
    for (int k = 1; k < L; ++k) {
        float val = ur[dir ? (L - k) : k];
        float nsr = fmaf(zr, sr, fmaf(-zi, si, val));
        float nsi = fmaf(zr, si, zi * sr);
        sr = nsr; si = nsi;
        float c = fmaf(wr, sr, -wi * si);
#pragma unroll
        for (int m = 1; m < 16; m <<= 1) c += __shfl_xor(c, m, 64);
        if (n == 0) {
            int pos = dir ? (L - 1 - k) : k;
            if (k < Lh) yb[pos] = c;      // first visitor stores
            else        yb[pos] += c;     // second visitor accumulates
        }
    }
    __syncthreads();

    // epilogue: y = gelu(yb + D*u) at kept (downsampled) positions
    float Dh = Dp[h];
    int Lk = L / ds;
    for (int p = sub; p < Lk; p += 32) {
        int l = p * ds;
        float v = yb[l] + Dh * ur[l];
        float g = 0.5f * v * (1.0f + erff(v * 0.70710678118f));
        y[(size_t)gh * Lk + p] = g;
    }
}

// ---------------------------------------------------------------------------
// GLU GEMM: for each b:  a = ow[0:768]@y + ob[0:768], g = ow[768:]@y + ob[768:]
//           xr = a*sigmoid(g) + u[:, ::ds]      written as (B, 768, Lk)
// ---------------------------------------------------------------------------
__global__ void __launch_bounds__(256) gemm_glu_kernel(
    const float* __restrict__ y,    // (B, 768, Lk)
    const float* __restrict__ u,    // (B, 768, Lk*ds)  residual source
    const float* __restrict__ ow,   // (1536, 768)
    const float* __restrict__ ob,   // (1536)
    float* __restrict__ xr,         // (B, 768, Lk)
    int Lk, int ds)
{
    __shared__ __align__(16) float as[64][68];  // [dd][kk]
    __shared__ __align__(16) float gs[64][68];
    __shared__ __align__(16) float bs[64][68];  // [kk][ll]
    int tid = threadIdx.x;
    int l0 = blockIdx.x * 64;
    int d0 = blockIdx.y * 64;
    int b  = blockIdx.z;
    int tl = tid & 15, td = tid >> 4;

    float acc_a[4][4] = {}, acc_g[4][4] = {};
    const float* ybase = y + (size_t)b * HDIM * Lk;

    for (int k0 = 0; k0 < HDIM; k0 += 64) {
        for (int p = tid; p < 4096; p += 256) {
            int kk = p & 63, dd = p >> 6;
            as[dd][kk] = ow[(size_t)(d0 + dd) * HDIM + k0 + kk];
            gs[dd][kk] = ow[(size_t)(d0 + dd + 768) * HDIM + k0 + kk];
        }
        for (int p = tid; p < 4096; p += 256) {
            int ll = p & 63, kk = p >> 6;
            bs[kk][ll] = ybase[(size_t)(k0 + kk) * Lk + l0 + ll];
        }
        __syncthreads();
#pragma unroll 8
        for (int kk = 0; kk < 64; ++kk) {
            float4 bv = *(const float4*)&bs[kk][tl * 4];
            float bb[4] = {bv.x, bv.y, bv.z, bv.w};
#pragma unroll
            for (int i = 0; i < 4; ++i) {
                float av = as[td * 4 + i][kk];
                float gv = gs[td * 4 + i][kk];
#pragma unroll
                for (int j = 0; j < 4; ++j) {
                    acc_a[i][j] = fmaf(av, bb[j], acc_a[i][j]);
                    acc_g[i][j] = fmaf(gv, bb[j], acc_g[i][j]);
                }
            }
        }
        __syncthreads();
    }

#pragma unroll
    for (int i = 0; i < 4; ++i) {
        int d = d0 + td * 4 + i;
        float ba = ob[d], bg = ob[d + 768];
        const float* urow = u + ((size_t)b * HDIM + d) * (size_t)(Lk * ds);
        float o[4];
#pragma unroll
        for (int j = 0; j < 4; ++j) {
            int l = l0 + tl * 4 + j;
            float a = acc_a[i][j] + ba;
            float g = acc_g[i][j] + bg;
            float sg = 1.0f / (1.0f + expf(-g));
            o[j] = fmaf(a, sg, urow[(size_t)l * ds]);
        }
        *(float4*)&xr[((size_t)b * HDIM + d) * Lk + l0 + tl * 4] =
            make_float4(o[0], o[1], o[2], o[3]);
    }
}

// ---------------------------------------------------------------------------
// LayerNorm over H (channel dim) of (B, H, Lk); 16 l's x 16 h-groups per block.
// ---------------------------------------------------------------------------
__global__ void __launch_bounds__(256) ln_kernel(
    const float* __restrict__ x, float* __restrict__ dst,
    const float* __restrict__ nw, const float* __restrict__ nb, int Lk)
{
    __shared__ float ss[16][17], qq[16][17], mus[16], rss[16];
    int tid = threadIdx.x;
    int lo = tid & 15, hg = tid >> 4;
    int b = blockIdx.y;
    int l = blockIdx.x * 16 + lo;
    const float* base = x + (size_t)b * HDIM * Lk + l;
    float s = 0.f, q = 0.f;
    for (int hh = hg; hh < HDIM; hh += 16) {
        float v = base[(size_t)hh * Lk];
        s += v; q = fmaf(v, v, q);
    }
    ss[hg][lo] = s; qq[hg][lo] = q;
    __syncthreads();
    if (hg == 0) {
        float S = 0.f, Q = 0.f;
#pragma unroll
        for (int t2 = 0; t2 < 16; ++t2) { S += ss[t2][lo]; Q += qq[t2][lo]; }
        float mu = S * (1.0f / HDIM);
        float var = Q * (1.0f / HDIM) - mu * mu;
        mus[lo] = mu; rss[lo] = rsqrtf(var + 1e-5f);
    }
    __syncthreads();
    float mu = mus[lo], rs = rss[lo];
    float* dbase = dst + (size_t)b * HDIM * Lk + l;
    for (int hh = hg; hh < HDIM; hh += 16) {
        float v = base[(size_t)hh * Lk];
        dbase[(size_t)hh * Lk] = (v - mu) * rs * nw[hh] + nb[hh];
    }
}

// ---------------------------------------------------------------------------
// Head: out[b,l,o] = sum_h u[b,h,l]*wout[h,o] + wb[o]  (float32 output!)
// ---------------------------------------------------------------------------
__global__ void __launch_bounds__(256) head_kernel(
    const float* __restrict__ u,      // (B, 768, Lk)
    const float* __restrict__ wout,   // (768, 38)
    const float* __restrict__ wb,     // (38)
    float* __restrict__ out,          // (B, Lk, 38) f32
    int Lk)
{
    __shared__ float wsh[64][40];
    int tid = threadIdx.x;
    int lt = tid & 63, og = tid >> 6;
    int b = blockIdx.y;
    int l = blockIdx.x * 64 + lt;
    float acc[10];
#pragma unroll
    for (int k = 0; k < 10; ++k) acc[k] = 0.f;
    for (int c0 = 0; c0 < HDIM; c0 += 64) {
        for (int p = tid; p < 64 * 38; p += 256) {
            int hh = p / 38, o = p - hh * 38;
            wsh[hh][o] = wout[(size_t)(c0 + hh) * 38 + o];
        }
        __syncthreads();
        for (int hh = 0; hh < 64; ++hh) {
            float uv = u[((size_t)b * HDIM + c0 + hh) * Lk + l];
#pragma unroll
            for (int k = 0; k < 10; ++k) {
                int o = og + 4 * k;
                if (o < 38) acc[k] = fmaf(uv, wsh[hh][o], acc[k]);
            }
        }
        __syncthreads();
    }
#pragma unroll
    for (int k = 0; k < 10; ++k) {
        int o = og + 4 * k;
        if (o < 38)
            out[((size_t)b * Lk + l) * 38 + o] = acc[k] + wb[o];
    }
}

// ---------------------------------------------------------------------------
extern "C" void kernel_launch(void* const* d_in, const int* in_sizes, int n_in,
                              void* d_out, int out_size, void* d_ws, size_t ws_size,
                              hipStream_t stream)
{
    (void)in_sizes; (void)n_in; (void)out_size; (void)ws_size;
    const float* x_raw      = (const float*)d_in[1];
    const float* enc_w1     = (const float*)d_in[3];
    const float* enc_b1     = (const float*)d_in[4];
    const float* enc_w2     = (const float*)d_in[5];
    const float* enc_b2     = (const float*)d_in[6];
    const float* log_dt     = (const float*)d_in[7];
    const float* log_A_real = (const float*)d_in[8];
    const float* A_imag     = (const float*)d_in[9];
    const float* C_ri       = (const float*)d_in[10];
    const float* Dp         = (const float*)d_in[11];
    const float* out_w      = (const float*)d_in[12];
    const float* out_b      = (const float*)d_in[13];
    const float* norm_w     = (const float*)d_in[14];
    const float* norm_b     = (const float*)d_in[15];
    const float* wout_w     = (const float*)d_in[16];
    const float* wout_b     = (const float*)d_in[17];

    char* ws = (char*)d_ws;
    float* Abuf = (float*)ws;                           // 50331648 B
    float* Bbuf = (float*)(ws + 50331648);              // 25165824 B
    float* Cbuf = (float*)(ws + 50331648 + 25165824);   // 25165824 B

    const int B = 8;

    enc_kernel<<<dim3(256, 12), 256, 0, stream>>>(x_raw, enc_w1, enc_b1, enc_w2, enc_b2, Abuf);

    int L = 2048;
    for (int i = 0; i < 6; ++i) {
        int ds = (i <= 2) ? 2 : 1;
        int Lk = L / ds;
        size_t lds = 2 * (size_t)L * sizeof(float);
        ssm_kernel<<<B * HDIM / 2, 64, lds, stream>>>(
            Abuf, Bbuf,
            log_dt + (size_t)i * HDIM,
            log_A_real + (size_t)i * HDIM * NSTATE,
            A_imag + (size_t)i * HDIM * NSTATE,
            C_ri + (size_t)i * 2 * HDIM * NSTATE * 2,
            Dp + (size_t)i * HDIM, L, ds);
        gemm_glu_kernel<<<dim3(Lk / 64, 12, B), 256, 0, stream>>>(
            Bbuf, Abuf,
            out_w + (size_t)i * 1536 * HDIM,
            out_b + (size_t)i * 1536,
            Cbuf, Lk, ds);
        ln_kernel<<<dim3(Lk / 16, B), 256, 0, stream>>>(
            Cbuf, Abuf, norm_w + (size_t)i * HDIM, norm_b + (size_t)i * HDIM, Lk);
        L = Lk;
    }

    head_kernel<<<dim3(L / 64, B), 256, 0, stream>>>(
        Abuf, wout_w, wout_b, (float*)d_out, L);
}

// Round 5
// 2806.316 us; speedup vs baseline: 1.3106x; 1.3106x over previous
//
#include <hip/hip_runtime.h>
#include <hip/hip_bf16.h>
#include <math.h>

#define HDIM 768
#define NSTATE 16
#define CHUNK 64

// ---------------------------------------------------------------------------
// Encoder: u0[b,j,l] = (softsign(x_raw @ W1 + b1) @ W2 + b2)[b,l,j]
// ---------------------------------------------------------------------------
__global__ void __launch_bounds__(256) enc_kernel(
    const float* __restrict__ xraw,   // (B*2048, 8)
    const float* __restrict__ w1,     // (8, 768)
    const float* __restrict__ b1,     // (768)
    const float* __restrict__ w2,     // (768, 768)
    const float* __restrict__ b2,     // (768)
    float* __restrict__ u0)           // (B, 768, 2048)
{
    __shared__ __align__(16) float xs[8][65];     // [q][row]
    __shared__ __align__(16) float hs[64][68];    // [kk][row]
    __shared__ __align__(16) float ws2[64][68];   // [kk][jj]
    int tid = threadIdx.x;
    int r0 = blockIdx.x * 64;
    int j0 = blockIdx.y * 64;
    int b  = r0 >> 11;
    int l0 = r0 & 2047;
    int tl = tid & 15, td = tid >> 4;

    for (int p = tid; p < 512; p += 256) {
        xs[p & 7][p >> 3] = xraw[(size_t)r0 * 8 + p];
    }
    __syncthreads();

    float acc[4][4] = {};
    for (int k0 = 0; k0 < HDIM; k0 += 64) {
        for (int p = tid; p < 4096; p += 256) {
            int rr = p & 63, kk = p >> 6;
            float hv = b1[k0 + kk];
#pragma unroll
            for (int q = 0; q < 8; ++q)
                hv = fmaf(xs[q][rr], w1[q * HDIM + k0 + kk], hv);
            hv = hv / (1.0f + fabsf(hv));
            hs[kk][rr] = hv;
        }
        for (int p = tid; p < 4096; p += 256) {
            int jj = p & 63, kk = p >> 6;
            ws2[kk][jj] = w2[(size_t)(k0 + kk) * HDIM + j0 + jj];
        }
        __syncthreads();
#pragma unroll 8
        for (int kk = 0; kk < 64; ++kk) {
            float4 hv = *(const float4*)&hs[kk][tl * 4];
            float hh[4] = {hv.x, hv.y, hv.z, hv.w};
#pragma unroll
            for (int i = 0; i < 4; ++i) {
                float wv = ws2[kk][td * 4 + i];
#pragma unroll
                for (int j = 0; j < 4; ++j)
                    acc[i][j] = fmaf(wv, hh[j], acc[i][j]);
            }
        }
        __syncthreads();
    }
#pragma unroll
    for (int i = 0; i < 4; ++i) {
        int j = j0 + td * 4 + i;
        float bb = b2[j];
        float4 ov;
        ov.x = acc[i][0] + bb; ov.y = acc[i][1] + bb;
        ov.z = acc[i][2] + bb; ov.w = acc[i][3] + bb;
        *(float4*)&u0[((size_t)b * HDIM + j) * 2048 + l0 + tl * 4] = ov;
    }
}

// ---------------------------------------------------------------------------
// Chunk-parallel bidirectional SSM.
// Thread = (row, chunk). Both directions per thread over its CHUNK positions.
// Phases: A1 fwd-local -> LDS, B-fwd prefix, C1 fwd-emit (tmp = cf + D*u),
//         A2 bwd-local -> LDS, B-bwd suffix, C2 bwd-emit (y = gelu(tmp+cb)).
// ---------------------------------------------------------------------------
__global__ void __launch_bounds__(256) ssm_chunk_kernel(
    const float* __restrict__ u,        // (rows=6144, L)
    float* __restrict__ y,              // (rows, L/ds)
    float* __restrict__ tmp,            // (rows, L/ds) scratch
    const float* __restrict__ log_dt,   // (H)
    const float* __restrict__ log_A_real, // (H,16)
    const float* __restrict__ A_imag,   // (H,16)
    const float* __restrict__ C_ri,     // (2,H,16,2)
    const float* __restrict__ Dp,       // (H)
    int L, int ds, int lognch)
{
    __shared__ float tls[256 * 33];     // per-thread 32 floats, stride 33
    int tid = threadIdx.x;
    int nch = 1 << lognch;              // chunks per row = L/64
    int lr  = tid >> lognch;
    int j   = tid & (nch - 1);
    int rows_per_block = 256 >> lognch;
    int row = blockIdx.x * rows_per_block + lr;
    int h   = row % HDIM;
    int c0  = j * CHUNK;
    const float* ur = u + (size_t)row * L;
    int Lk = L / ds;

    // --- discretization constants (registers) ---
    float dt = expf(log_dt[h]);
    float zr[16], zi[16], zCr[16], zCi[16];
    float w0r[16], w0i[16], w1r[16], w1i[16];
#pragma unroll
    for (int n = 0; n < NSTATE; ++n) {
        float Ar = -expf(log_A_real[h * NSTATE + n]);
        float Ai = A_imag[h * NSTATE + n];
        float er = expf(dt * Ar);
        float th = dt * Ai;
        zr[n] = er * cosf(th); zi[n] = er * sinf(th);
        float erC = expf((float)CHUNK * dt * Ar);
        float thC = (float)CHUNK * dt * Ai;
        zCr[n] = erC * cosf(thC); zCi[n] = erC * sinf(thC);
        float den = Ar * Ar + Ai * Ai;
        float t0 = zr[n] - 1.0f;
        float dBr = (t0 * Ar + zi[n] * Ai) / den;
        float dBi = (zi[n] * Ar - t0 * Ai) / den;
        float C0r = C_ri[((0 * HDIM + h) * NSTATE + n) * 2 + 0];
        float C0i = C_ri[((0 * HDIM + h) * NSTATE + n) * 2 + 1];
        float C1r = C_ri[((1 * HDIM + h) * NSTATE + n) * 2 + 0];
        float C1i = C_ri[((1 * HDIM + h) * NSTATE + n) * 2 + 1];
        w0r[n] = 2.0f * (C0r * dBr - C0i * dBi);
        w0i[n] = 2.0f * (C0r * dBi + C0i * dBr);
        w1r[n] = 2.0f * (C1r * dBr - C1i * dBi);
        w1i[n] = 2.0f * (C1r * dBi + C1i * dBr);
    }

    float* myT = &tls[tid * 33];

    // --- A1: forward local end-state (zero init) ---
    {
        float sr_[16] = {}, si_[16] = {};
#pragma unroll 4
        for (int i = 0; i < CHUNK; ++i) {
            float uf = ur[c0 + i];
#pragma unroll
            for (int n = 0; n < NSTATE; ++n) {
                float nr = fmaf(zr[n], sr_[n], fmaf(-zi[n], si_[n], uf));
                si_[n] = fmaf(zr[n], si_[n], zi[n] * sr_[n]);
                sr_[n] = nr;
            }
        }
#pragma unroll
        for (int n = 0; n < NSTATE; ++n) { myT[2 * n] = sr_[n]; myT[2 * n + 1] = si_[n]; }
    }
    __syncthreads();

    // --- B-fwd: incoming state S_j = sum_{i<j} zC^{j-1-i} Tf_i ---
    float Sr[16] = {}, Si[16] = {};
    for (int i = 0; i < j; ++i) {
        const float* T = &tls[(lr * nch + i) * 33];
#pragma unroll
        for (int n = 0; n < NSTATE; ++n) {
            float tr = T[2 * n], ti = T[2 * n + 1];
            float nr = fmaf(zCr[n], Sr[n], fmaf(-zCi[n], Si[n], tr));
            Si[n] = fmaf(zCr[n], Si[n], fmaf(zCi[n], Sr[n], ti));
            Sr[n] = nr;
        }
    }

    // --- C1: forward emit: tmp[p/ds] = cf(p) + D*u[p] at kept p ---
    float Dh = Dp[h];
    float* trow = tmp + (size_t)row * Lk;
#pragma unroll 4
    for (int i = 0; i < CHUNK; ++i) {
        float uf = ur[c0 + i];
        float cf0 = 0.f, cf1 = 0.f, cf2 = 0.f, cf3 = 0.f;
#pragma unroll
        for (int n = 0; n < NSTATE; ++n) {
            float nr = fmaf(zr[n], Sr[n], fmaf(-zi[n], Si[n], uf));
            Si[n] = fmaf(zr[n], Si[n], zi[n] * Sr[n]);
            Sr[n] = nr;
            float c = fmaf(w0r[n], Sr[n], -w0i[n] * Si[n]);
            if ((n & 3) == 0) cf0 += c; else if ((n & 3) == 1) cf1 += c;
            else if ((n & 3) == 2) cf2 += c; else cf3 += c;
        }
        if ((i & (ds - 1)) == 0)
            trow[(c0 + i) / ds] = fmaf(Dh, uf, (cf0 + cf1) + (cf2 + cf3));
    }
    __syncthreads();   // all B-fwd LDS reads done before A2 overwrites

    // --- A2: backward local end-state (zero init): Tb_j ---
    {
        float sr_[16] = {}, si_[16] = {};
#pragma unroll 4
        for (int m = 0; m < CHUNK; ++m) {
            int idx = c0 + CHUNK - m;
            float ub = (idx < L) ? ur[idx] : 0.f;
#pragma unroll
            for (int n = 0; n < NSTATE; ++n) {
                float nr = fmaf(zr[n], sr_[n], fmaf(-zi[n], si_[n], ub));
                si_[n] = fmaf(zr[n], si_[n], zi[n] * sr_[n]);
                sr_[n] = nr;
            }
        }
#pragma unroll
        for (int n = 0; n < NSTATE; ++n) { myT[2 * n] = sr_[n]; myT[2 * n + 1] = si_[n]; }
    }
    __syncthreads();

    // --- B-bwd: incoming-from-right state E = sum_{i>j} zC^{i-j-1} Tb_i ---
    float Er[16] = {}, Ei[16] = {};
    for (int i = nch - 1; i > j; --i) {
        const float* T = &tls[(lr * nch + i) * 33];
#pragma unroll
        for (int n = 0; n < NSTATE; ++n) {
            float tr = T[2 * n], ti = T[2 * n + 1];
            float nr = fmaf(zCr[n], Er[n], fmaf(-zCi[n], Ei[n], tr));
            Ei[n] = fmaf(zCr[n], Ei[n], fmaf(zCi[n], Er[n], ti));
            Er[n] = nr;
        }
    }

    // --- C2: backward emit: y = gelu(tmp + cb) at kept p (descending) ---
    float* yrow = y + (size_t)row * Lk;
#pragma unroll 4
    for (int m = 0; m < CHUNK; ++m) {
        int idx = c0 + CHUNK - m;
        float ub = (idx < L) ? ur[idx] : 0.f;
        float cb0 = 0.f, cb1 = 0.f, cb2 = 0.f, cb3 = 0.f;
#pragma unroll
        for (int n = 0; n < NSTATE; ++n) {
            float nr = fmaf(zr[n], Er[n], fmaf(-zi[n], Ei[n], ub));
            Ei[n] = fmaf(zr[n], Ei[n], zi[n] * Er[n]);
            Er[n] = nr;
            float c = fmaf(w1r[n], Er[n], -w1i[n] * Ei[n]);
            if ((n & 3) == 0) cb0 += c; else if ((n & 3) == 1) cb1 += c;
            else if ((n & 3) == 2) cb2 += c; else cb3 += c;
        }
        int p = c0 + CHUNK - 1 - m;
        if ((p & (ds - 1)) == 0) {
            float v = trow[p / ds] + (cb0 + cb1) + (cb2 + cb3);
            float g = 0.5f * v * (1.0f + erff(v * 0.70710678118f));
            yrow[p / ds] = g;
        }
    }
}

// ---------------------------------------------------------------------------
// GLU GEMM: a = ow[0:768]@y, g = ow[768:]@y;  xr = a*sigmoid(g) + u[:, ::ds]
// ---------------------------------------------------------------------------
__global__ void __launch_bounds__(256) gemm_glu_kernel(
    const float* __restrict__ y,    // (B, 768, Lk)
    const float* __restrict__ u,    // (B, 768, Lk*ds)
    const float* __restrict__ ow,   // (1536, 768)
    const float* __restrict__ ob,   // (1536)
    float* __restrict__ xr,         // (B, 768, Lk)
    int Lk, int ds)
{
    __shared__ __align__(16) float as[64][68];
    __shared__ __align__(16) float gs[64][68];
    __shared__ __align__(16) float bs[64][68];
    int tid = threadIdx.x;
    int l0 = blockIdx.x * 64;
    int d0 = blockIdx.y * 64;
    int b  = blockIdx.z;
    int tl = tid & 15, td = tid >> 4;

    float acc_a[4][4] = {}, acc_g[4][4] = {};
    const float* ybase = y + (size_t)b * HDIM * Lk;

    for (int k0 = 0; k0 < HDIM; k0 += 64) {
        for (int p = tid; p < 4096; p += 256) {
            int kk = p & 63, dd = p >> 6;
            as[dd][kk] = ow[(size_t)(d0 + dd) * HDIM + k0 + kk];
            gs[dd][kk] = ow[(size_t)(d0 + dd + 768) * HDIM + k0 + kk];
        }
        for (int p = tid; p < 4096; p += 256) {
            int ll = p & 63, kk = p >> 6;
            bs[kk][ll] = ybase[(size_t)(k0 + kk) * Lk + l0 + ll];
        }
        __syncthreads();
#pragma unroll 8
        for (int kk = 0; kk < 64; ++kk) {
            float4 bv = *(const float4*)&bs[kk][tl * 4];
            float bb[4] = {bv.x, bv.y, bv.z, bv.w};
#pragma unroll
            for (int i = 0; i < 4; ++i) {
                float av = as[td * 4 + i][kk];
                float gv = gs[td * 4 + i][kk];
#pragma unroll
                for (int j = 0; j < 4; ++j) {
                    acc_a[i][j] = fmaf(av, bb[j], acc_a[i][j]);
                    acc_g[i][j] = fmaf(gv, bb[j], acc_g[i][j]);
                }
            }
        }
        __syncthreads();
    }

#pragma unroll
    for (int i = 0; i < 4; ++i) {
        int d = d0 + td * 4 + i;
        float ba = ob[d], bg = ob[d + 768];
        const float* urow = u + ((size_t)b * HDIM + d) * (size_t)(Lk * ds);
        float o[4];
#pragma unroll
        for (int j = 0; j < 4; ++j) {
            int l = l0 + tl * 4 + j;
            float a = acc_a[i][j] + ba;
            float g = acc_g[i][j] + bg;
            float sg = 1.0f / (1.0f + expf(-g));
            o[j] = fmaf(a, sg, urow[(size_t)l * ds]);
        }
        *(float4*)&xr[((size_t)b * HDIM + d) * Lk + l0 + tl * 4] =
            make_float4(o[0], o[1], o[2], o[3]);
    }
}

// ---------------------------------------------------------------------------
// LayerNorm over H of (B, H, Lk)
// ---------------------------------------------------------------------------
__global__ void __launch_bounds__(256) ln_kernel(
    const float* __restrict__ x, float* __restrict__ dst,
    const float* __restrict__ nw, const float* __restrict__ nb, int Lk)
{
    __shared__ float ss[16][17], qq[16][17], mus[16], rss[16];
    int tid = threadIdx.x;
    int lo = tid & 15, hg = tid >> 4;
    int b = blockIdx.y;
    int l = blockIdx.x * 16 + lo;
    const float* base = x + (size_t)b * HDIM * Lk + l;
    float s = 0.f, q = 0.f;
    for (int hh = hg; hh < HDIM; hh += 16) {
        float v = base[(size_t)hh * Lk];
        s += v; q = fmaf(v, v, q);
    }
    ss[hg][lo] = s; qq[hg][lo] = q;
    __syncthreads();
    if (hg == 0) {
        float S = 0.f, Q = 0.f;
#pragma unroll
        for (int t2 = 0; t2 < 16; ++t2) { S += ss[t2][lo]; Q += qq[t2][lo]; }
        float mu = S * (1.0f / HDIM);
        float var = Q * (1.0f / HDIM) - mu * mu;
        mus[lo] = mu; rss[lo] = rsqrtf(var + 1e-5f);
    }
    __syncthreads();
    float mu = mus[lo], rs = rss[lo];
    float* dbase = dst + (size_t)b * HDIM * Lk + l;
    for (int hh = hg; hh < HDIM; hh += 16) {
        float v = base[(size_t)hh * Lk];
        dbase[(size_t)hh * Lk] = (v - mu) * rs * nw[hh] + nb[hh];
    }
}

// ---------------------------------------------------------------------------
// Head: out[b,l,o] = sum_h u[b,h,l]*wout[h,o] + wb[o]  (f32 out)
// ---------------------------------------------------------------------------
__global__ void __launch_bounds__(256) head_kernel(
    const float* __restrict__ u,      // (B, 768, Lk)
    const float* __restrict__ wout,   // (768, 38)
    const float* __restrict__ wb,     // (38)
    float* __restrict__ out,          // (B, Lk, 38)
    int Lk)
{
    __shared__ float wsh[64][40];
    int tid = threadIdx.x;
    int lt = tid & 63, og = tid >> 6;
    int b = blockIdx.y;
    int l = blockIdx.x * 64 + lt;
    float acc[10];
#pragma unroll
    for (int k = 0; k < 10; ++k) acc[k] = 0.f;
    for (int c0 = 0; c0 < HDIM; c0 += 64) {
        for (int p = tid; p < 64 * 38; p += 256) {
            int hh = p / 38, o = p - hh * 38;
            wsh[hh][o] = wout[(size_t)(c0 + hh) * 38 + o];
        }
        __syncthreads();
        for (int hh = 0; hh < 64; ++hh) {
            float uv = u[((size_t)b * HDIM + c0 + hh) * Lk + l];
#pragma unroll
            for (int k = 0; k < 10; ++k) {
                int o = og + 4 * k;
                if (o < 38) acc[k] = fmaf(uv, wsh[hh][o], acc[k]);
            }
        }
        __syncthreads();
    }
#pragma unroll
    for (int k = 0; k < 10; ++k) {
        int o = og + 4 * k;
        if (o < 38)
            out[((size_t)b * Lk + l) * 38 + o] = acc[k] + wb[o];
    }
}

// ---------------------------------------------------------------------------
extern "C" void kernel_launch(void* const* d_in, const int* in_sizes, int n_in,
                              void* d_out, int out_size, void* d_ws, size_t ws_size,
                              hipStream_t stream)
{
    (void)in_sizes; (void)n_in; (void)out_size; (void)ws_size;
    const float* x_raw      = (const float*)d_in[1];
    const float* enc_w1     = (const float*)d_in[3];
    const float* enc_b1     = (const float*)d_in[4];
    const float* enc_w2     = (const float*)d_in[5];
    const float* enc_b2     = (const float*)d_in[6];
    const float* log_dt     = (const float*)d_in[7];
    const float* log_A_real = (const float*)d_in[8];
    const float* A_imag     = (const float*)d_in[9];
    const float* C_ri       = (const float*)d_in[10];
    const float* Dp         = (const float*)d_in[11];
    const float* out_w      = (const float*)d_in[12];
    const float* out_b      = (const float*)d_in[13];
    const float* norm_w     = (const float*)d_in[14];
    const float* norm_b     = (const float*)d_in[15];
    const float* wout_w     = (const float*)d_in[16];
    const float* wout_b     = (const float*)d_in[17];

    char* ws = (char*)d_ws;
    float* Abuf = (float*)ws;                           // u buffer (B,H,L)
    float* Bbuf = (float*)(ws + 50331648);              // gelu(y) buffer
    float* Cbuf = (float*)(ws + 50331648 + 25165824);   // tmp during SSM, then xr

    const int B = 8;

    enc_kernel<<<dim3(256, 12), 256, 0, stream>>>(x_raw, enc_w1, enc_b1, enc_w2, enc_b2, Abuf);

    int L = 2048;
    for (int i = 0; i < 6; ++i) {
        int ds = (i <= 2) ? 2 : 1;
        int Lk = L / ds;
        int lognch = 31 - __builtin_clz(L / CHUNK);   // L=2048->5 ... 256->2
        ssm_chunk_kernel<<<24 << lognch, 256, 0, stream>>>(
            Abuf, Bbuf, Cbuf,
            log_dt + (size_t)i * HDIM,
            log_A_real + (size_t)i * HDIM * NSTATE,
            A_imag + (size_t)i * HDIM * NSTATE,
            C_ri + (size_t)i * 2 * HDIM * NSTATE * 2,
            Dp + (size_t)i * HDIM, L, ds, lognch);
        gemm_glu_kernel<<<dim3(Lk / 64, 12, B), 256, 0, stream>>>(
            Bbuf, Abuf,
            out_w + (size_t)i * 1536 * HDIM,
            out_b + (size_t)i * 1536,
            Cbuf, Lk, ds);
        ln_kernel<<<dim3(Lk / 16, B), 256, 0, stream>>>(
            Cbuf, Abuf, norm_w + (size_t)i * HDIM, norm_b + (size_t)i * HDIM, Lk);
        L = Lk;
    }

    head_kernel<<<dim3(L / 64, B), 256, 0, stream>>>(
        Abuf, wout_w, wout_b, (float*)d_out, L);
}

// Round 6
// 1699.257 us; speedup vs baseline: 2.1644x; 1.6515x over previous
//
#include <hip/hip_runtime.h>
#include <hip/hip_bf16.h>
#include <math.h>

#define HDIM 768
#define NSTATE 16
#define CHUNK 64

typedef __attribute__((ext_vector_type(8))) short bf16x8;
typedef __attribute__((ext_vector_type(4))) float f32x4;
typedef __attribute__((ext_vector_type(4))) unsigned int u32x4;

__device__ __forceinline__ unsigned short f2bf(float f) {
    union { float f; unsigned int u; } v; v.f = f;
    unsigned int r = v.u + 0x7fff + ((v.u >> 16) & 1);   // round-to-nearest-even
    return (unsigned short)(r >> 16);
}

// ---------------------------------------------------------------------------
// wconv: f32 -> bf16 flat copy (8 elems/thread)
// ---------------------------------------------------------------------------
__global__ void __launch_bounds__(256) wconv_kernel(
    const float* __restrict__ src, unsigned short* __restrict__ dst, int n8)
{
    int t = blockIdx.x * 256 + threadIdx.x;
    if (t >= n8) return;
    const float* s = src + (size_t)t * 8;
    float4 a = *(const float4*)s, b = *(const float4*)(s + 4);
    union { unsigned short us[8]; u32x4 v; } o;
    o.us[0] = f2bf(a.x); o.us[1] = f2bf(a.y); o.us[2] = f2bf(a.z); o.us[3] = f2bf(a.w);
    o.us[4] = f2bf(b.x); o.us[5] = f2bf(b.y); o.us[6] = f2bf(b.z); o.us[7] = f2bf(b.w);
    *(u32x4*)(dst + (size_t)t * 8) = o.v;
}

// ---------------------------------------------------------------------------
// w2t: transpose + convert enc_w2 (768k x 768j) -> (768j x 768k) bf16
// ---------------------------------------------------------------------------
__global__ void __launch_bounds__(256) w2t_kernel(
    const float* __restrict__ w2, unsigned short* __restrict__ w2t)
{
    int T = blockIdx.x * 256 + threadIdx.x;   // < 768*96
    int j = T / 96, kc = T - j * 96;
    union { unsigned short us[8]; u32x4 v; } o;
#pragma unroll
    for (int i = 0; i < 8; ++i)
        o.us[i] = f2bf(w2[(size_t)(kc * 8 + i) * HDIM + j]);
    *(u32x4*)(w2t + (size_t)j * HDIM + kc * 8) = o.v;
}

// ---------------------------------------------------------------------------
// hprep: h[r][k] = softsign(x_raw[r] @ w1[:,k] + b1[k]) -> bf16 (16384, 768)
// ---------------------------------------------------------------------------
__global__ void __launch_bounds__(256) hprep_kernel(
    const float* __restrict__ xraw, const float* __restrict__ w1,
    const float* __restrict__ b1, unsigned short* __restrict__ hbf)
{
    __shared__ float w1s[8 * HDIM];
    __shared__ float b1s[HDIM];
    int tid = threadIdx.x;
    for (int p = tid; p < 8 * HDIM; p += 256) w1s[p] = w1[p];
    for (int p = tid; p < HDIM; p += 256) b1s[p] = b1[p];
    __syncthreads();
    int T = blockIdx.x * 256 + tid;           // < 16384*96
    int r = T / 96, kc = T - r * 96;
    float4 xa = *(const float4*)(xraw + (size_t)r * 8);
    float4 xb = *(const float4*)(xraw + (size_t)r * 8 + 4);
    float xq[8] = {xa.x, xa.y, xa.z, xa.w, xb.x, xb.y, xb.z, xb.w};
    float acc[8];
#pragma unroll
    for (int i = 0; i < 8; ++i) acc[i] = b1s[kc * 8 + i];
#pragma unroll
    for (int q = 0; q < 8; ++q)
#pragma unroll
        for (int i = 0; i < 8; ++i)
            acc[i] = fmaf(xq[q], w1s[q * HDIM + kc * 8 + i], acc[i]);
    union { unsigned short us[8]; u32x4 v; } o;
#pragma unroll
    for (int i = 0; i < 8; ++i) {
        float h = acc[i] / (1.0f + fabsf(acc[i]));
        o.us[i] = f2bf(h);
    }
    *(u32x4*)(hbf + (size_t)r * HDIM + kc * 8) = o.v;
}

// ---------------------------------------------------------------------------
// enc_mfma: u0 (B,768,2048) f32 = w2t(768j,768k) @ hbf(16384r,768k)^T + b2
// block: 64j x 128r tile; 4 waves (2x2), wave = 32j x 64r; K-step 64, dbuf LDS.
// LDS rows: 0-63 W, 64-191 H; row = 64 bf16 (128B), XOR-swizzled in 16B units.
// ---------------------------------------------------------------------------
__global__ void __launch_bounds__(256) enc_mfma_kernel(
    const unsigned short* __restrict__ w2t,
    const unsigned short* __restrict__ hbf,
    const float* __restrict__ b2,
    float* __restrict__ u0)
{
    __shared__ unsigned short lds[2][192 * 64];
    int tid = threadIdx.x;
    int j0 = blockIdx.x * 64;
    int r0 = blockIdx.y * 128;
    int w = tid >> 6, lane = tid & 63;
    int wj = w >> 1, wl = w & 1;
    f32x4 acc[2][4];
    f32x4 zf = {0.f, 0.f, 0.f, 0.f};
#pragma unroll
    for (int dg = 0; dg < 2; ++dg)
#pragma unroll
        for (int cg = 0; cg < 4; ++cg) acc[dg][cg] = zf;

    u32x4 stg[6];
#define ENC_LOAD(kt) do { int k0_ = (kt) * 64; \
    _Pragma("unroll") for (int s = 0; s < 6; ++s) { \
        int c = s * 256 + tid; int row = c >> 3, m = c & 7; \
        const unsigned short* g = (row < 64) \
            ? (w2t + (size_t)(j0 + row) * HDIM + k0_ + m * 8) \
            : (hbf + (size_t)(r0 + row - 64) * HDIM + k0_ + m * 8); \
        stg[s] = *(const u32x4*)g; } } while (0)
#define ENC_WRITE(bi) do { \
    _Pragma("unroll") for (int s = 0; s < 6; ++s) { \
        int c = s * 256 + tid; int row = c >> 3, m = c & 7; \
        *(u32x4*)&lds[bi][row * 64 + 8 * (m ^ (row & 7))] = stg[s]; } } while (0)

    ENC_LOAD(0); ENC_WRITE(0);
    int cur = 0;
    for (int t = 0; t < 12; ++t) {
        __syncthreads();
        if (t < 11) ENC_LOAD(t + 1);
#pragma unroll
        for (int kh = 0; kh < 2; ++kh) {
            int kg = kh * 4 + (lane >> 4);
            bf16x8 af[2], bfr[4];
#pragma unroll
            for (int dg = 0; dg < 2; ++dg) {
                int rA = wj * 32 + dg * 16 + (lane & 15);
                af[dg] = *(bf16x8*)&lds[cur][rA * 64 + 8 * (kg ^ (rA & 7))];
            }
#pragma unroll
            for (int cg = 0; cg < 4; ++cg) {
                int rB = 64 + wl * 64 + cg * 16 + (lane & 15);
                bfr[cg] = *(bf16x8*)&lds[cur][rB * 64 + 8 * (kg ^ (rB & 7))];
            }
#pragma unroll
            for (int dg = 0; dg < 2; ++dg)
#pragma unroll
                for (int cg = 0; cg < 4; ++cg)
                    acc[dg][cg] = __builtin_amdgcn_mfma_f32_16x16x32_bf16(
                        af[dg], bfr[cg], acc[dg][cg], 0, 0, 0);
        }
        if (t < 11) ENC_WRITE(cur ^ 1);
        cur ^= 1;
    }
    int b = r0 >> 11;
    int l0 = r0 & 2047;
#pragma unroll
    for (int dg = 0; dg < 2; ++dg) {
        int j = j0 + wj * 32 + dg * 16 + ((lane >> 4) << 2);
#pragma unroll
        for (int cg = 0; cg < 4; ++cg) {
            int l = l0 + wl * 64 + cg * 16 + (lane & 15);
#pragma unroll
            for (int i = 0; i < 4; ++i)
                u0[((size_t)(b * HDIM + j + i)) * 2048 + l] = acc[dg][cg][i] + b2[j + i];
        }
    }
#undef ENC_LOAD
#undef ENC_WRITE
}

// ---------------------------------------------------------------------------
// glu_mfma: a = W[0:768]@Y, g = W[768:]@Y (bf16 MFMA, f32 acc);
//           xr = (a+ba)*sigmoid(g+bg) + u[:, ::ds]   out (B,768,Lk) f32
// LDS rows: 0-63 Wa, 64-127 Wg, 128-255 Y(l). Same swizzle/dbuf as enc.
// ---------------------------------------------------------------------------
__global__ void __launch_bounds__(256) glu_mfma_kernel(
    const unsigned short* __restrict__ wbf,   // (1536, 768) bf16
    const unsigned short* __restrict__ yt,    // (B, Lk, 768) bf16
    const float* __restrict__ u,              // (B, 768, Lk*ds)
    const float* __restrict__ ob,             // (1536)
    float* __restrict__ xr,                   // (B, 768, Lk)
    int Lk, int ds)
{
    __shared__ unsigned short lds[2][256 * 64];
    int tid = threadIdx.x;
    int d0 = blockIdx.x * 64;
    int l0 = blockIdx.y * 128;
    int b  = blockIdx.z;
    int w = tid >> 6, lane = tid & 63;
    int wd = w >> 1, wl = w & 1;
    f32x4 accA[2][4], accG[2][4];
    f32x4 zf = {0.f, 0.f, 0.f, 0.f};
#pragma unroll
    for (int dg = 0; dg < 2; ++dg)
#pragma unroll
        for (int cg = 0; cg < 4; ++cg) { accA[dg][cg] = zf; accG[dg][cg] = zf; }

    u32x4 stg[8];
#define GLU_LOAD(kt) do { int k0_ = (kt) * 64; \
    _Pragma("unroll") for (int s = 0; s < 8; ++s) { \
        int c = s * 256 + tid; int row = c >> 3, m = c & 7; \
        const unsigned short* g; \
        if (row < 64)       g = wbf + (size_t)(d0 + row) * HDIM + k0_ + m * 8; \
        else if (row < 128) g = wbf + (size_t)(768 + d0 + row - 64) * HDIM + k0_ + m * 8; \
        else g = yt + ((size_t)b * Lk + l0 + row - 128) * HDIM + k0_ + m * 8; \
        stg[s] = *(const u32x4*)g; } } while (0)
#define GLU_WRITE(bi) do { \
    _Pragma("unroll") for (int s = 0; s < 8; ++s) { \
        int c = s * 256 + tid; int row = c >> 3, m = c & 7; \
        *(u32x4*)&lds[bi][row * 64 + 8 * (m ^ (row & 7))] = stg[s]; } } while (0)

    GLU_LOAD(0); GLU_WRITE(0);
    int cur = 0;
    for (int t = 0; t < 12; ++t) {
        __syncthreads();
        if (t < 11) GLU_LOAD(t + 1);
#pragma unroll
        for (int kh = 0; kh < 2; ++kh) {
            int kg = kh * 4 + (lane >> 4);
            bf16x8 aa[2], ag[2], bfr[4];
#pragma unroll
            for (int dg = 0; dg < 2; ++dg) {
                int rA = wd * 32 + dg * 16 + (lane & 15);
                aa[dg] = *(bf16x8*)&lds[cur][rA * 64 + 8 * (kg ^ (rA & 7))];
                int rG = 64 + rA;
                ag[dg] = *(bf16x8*)&lds[cur][rG * 64 + 8 * (kg ^ (rG & 7))];
            }
#pragma unroll
            for (int cg = 0; cg < 4; ++cg) {
                int rB = 128 + wl * 64 + cg * 16 + (lane & 15);
                bfr[cg] = *(bf16x8*)&lds[cur][rB * 64 + 8 * (kg ^ (rB & 7))];
            }
#pragma unroll
            for (int dg = 0; dg < 2; ++dg)
#pragma unroll
                for (int cg = 0; cg < 4; ++cg) {
                    accA[dg][cg] = __builtin_amdgcn_mfma_f32_16x16x32_bf16(
                        aa[dg], bfr[cg], accA[dg][cg], 0, 0, 0);
                    accG[dg][cg] = __builtin_amdgcn_mfma_f32_16x16x32_bf16(
                        ag[dg], bfr[cg], accG[dg][cg], 0, 0, 0);
                }
        }
        if (t < 11) GLU_WRITE(cur ^ 1);
        cur ^= 1;
    }
    size_t L = (size_t)Lk * ds;
#pragma unroll
    for (int dg = 0; dg < 2; ++dg) {
        int d = d0 + wd * 32 + dg * 16 + ((lane >> 4) << 2);
#pragma unroll
        for (int cg = 0; cg < 4; ++cg) {
            int l = l0 + wl * 64 + cg * 16 + (lane & 15);
#pragma unroll
            for (int i = 0; i < 4; ++i) {
                float a = accA[dg][cg][i] + ob[d + i];
                float g = accG[dg][cg][i] + ob[d + i + 768];
                float sg = 1.0f / (1.0f + expf(-g));
                float res = u[((size_t)b * HDIM + d + i) * L + (size_t)l * ds];
                xr[((size_t)b * HDIM + d + i) * Lk + l] = fmaf(a, sg, res);
            }
        }
    }
#undef GLU_LOAD
#undef GLU_WRITE
}

// ---------------------------------------------------------------------------
// Chunk-parallel bidirectional SSM. Consecutive tids = consecutive rows (h)
// so the transposed bf16 y-write coalesces. Emits y_t (B, Lk, 768) bf16.
// ---------------------------------------------------------------------------
__global__ void __launch_bounds__(256) ssm_chunk_kernel(
    const float* __restrict__ u,            // (rows=6144, L)
    unsigned short* __restrict__ yt,        // (B, Lk, 768) bf16
    float* __restrict__ tmp,                // (rows, Lk) f32 scratch
    const float* __restrict__ log_dt,
    const float* __restrict__ log_A_real,
    const float* __restrict__ A_imag,
    const float* __restrict__ C_ri,
    const float* __restrict__ Dp,
    int L, int ds, int lognch)
{
    __shared__ float tls[256 * 33];
    int tid = threadIdx.x;
    int nch = 1 << lognch;
    int rpb = 256 >> lognch;
    int lr  = tid & (rpb - 1);
    int j   = tid >> (8 - lognch);
    int row = blockIdx.x * rpb + lr;
    int b   = row / HDIM;
    int h   = row - b * HDIM;
    int c0  = j * CHUNK;
    const float* ur = u + (size_t)row * L;
    int Lk = L / ds;

    float dt = expf(log_dt[h]);
    float zr[16], zi[16], zCr[16], zCi[16];
    float w0r[16], w0i[16], w1r[16], w1i[16];
#pragma unroll
    for (int n = 0; n < NSTATE; ++n) {
        float Ar = -expf(log_A_real[h * NSTATE + n]);
        float Ai = A_imag[h * NSTATE + n];
        float er = expf(dt * Ar);
        float th = dt * Ai;
        zr[n] = er * cosf(th); zi[n] = er * sinf(th);
        float erC = expf((float)CHUNK * dt * Ar);
        float thC = (float)CHUNK * dt * Ai;
        zCr[n] = erC * cosf(thC); zCi[n] = erC * sinf(thC);
        float den = Ar * Ar + Ai * Ai;
        float t0 = zr[n] - 1.0f;
        float dBr = (t0 * Ar + zi[n] * Ai) / den;
        float dBi = (zi[n] * Ar - t0 * Ai) / den;
        float C0r = C_ri[((0 * HDIM + h) * NSTATE + n) * 2 + 0];
        float C0i = C_ri[((0 * HDIM + h) * NSTATE + n) * 2 + 1];
        float C1r = C_ri[((1 * HDIM + h) * NSTATE + n) * 2 + 0];
        float C1i = C_ri[((1 * HDIM + h) * NSTATE + n) * 2 + 1];
        w0r[n] = 2.0f * (C0r * dBr - C0i * dBi);
        w0i[n] = 2.0f * (C0r * dBi + C0i * dBr);
        w1r[n] = 2.0f * (C1r * dBr - C1i * dBi);
        w1i[n] = 2.0f * (C1r * dBi + C1i * dBr);
    }

    float* myT = &tls[(lr * nch + j) * 33];

    // A1: forward local end-state
    {
        float sr_[16] = {}, si_[16] = {};
#pragma unroll 4
        for (int i = 0; i < CHUNK; ++i) {
            float uf = ur[c0 + i];
#pragma unroll
            for (int n = 0; n < NSTATE; ++n) {
                float nr = fmaf(zr[n], sr_[n], fmaf(-zi[n], si_[n], uf));
                si_[n] = fmaf(zr[n], si_[n], zi[n] * sr_[n]);
                sr_[n] = nr;
            }
        }
#pragma unroll
        for (int n = 0; n < NSTATE; ++n) { myT[2 * n] = sr_[n]; myT[2 * n + 1] = si_[n]; }
    }
    __syncthreads();

    // B-fwd prefix
    float Sr[16] = {}, Si[16] = {};
    for (int i = 0; i < j; ++i) {
        const float* T = &tls[(lr * nch + i) * 33];
#pragma unroll
        for (int n = 0; n < NSTATE; ++n) {
            float tr = T[2 * n], ti = T[2 * n + 1];
            float nr = fmaf(zCr[n], Sr[n], fmaf(-zCi[n], Si[n], tr));
            Si[n] = fmaf(zCr[n], Si[n], fmaf(zCi[n], Sr[n], ti));
            Sr[n] = nr;
        }
    }

    // C1: forward emit tmp = cf + D*u at kept positions
    float Dh = Dp[h];
    float* trow = tmp + (size_t)row * Lk;
#pragma unroll 4
    for (int i = 0; i < CHUNK; ++i) {
        float uf = ur[c0 + i];
        float cf0 = 0.f, cf1 = 0.f, cf2 = 0.f, cf3 = 0.f;
#pragma unroll
        for (int n = 0; n < NSTATE; ++n) {
            float nr = fmaf(zr[n], Sr[n], fmaf(-zi[n], Si[n], uf));
            Si[n] = fmaf(zr[n], Si[n], zi[n] * Sr[n]);
            Sr[n] = nr;
            float c = fmaf(w0r[n], Sr[n], -w0i[n] * Si[n]);
            if ((n & 3) == 0) cf0 += c; else if ((n & 3) == 1) cf1 += c;
            else if ((n & 3) == 2) cf2 += c; else cf3 += c;
        }
        if ((i & (ds - 1)) == 0)
            trow[(c0 + i) / ds] = fmaf(Dh, uf, (cf0 + cf1) + (cf2 + cf3));
    }
    __syncthreads();

    // A2: backward local end-state
    {
        float sr_[16] = {}, si_[16] = {};
#pragma unroll 4
        for (int m = 0; m < CHUNK; ++m) {
            int idx = c0 + CHUNK - m;
            float ub = (idx < L) ? ur[idx] : 0.f;
#pragma unroll
            for (int n = 0; n < NSTATE; ++n) {
                float nr = fmaf(zr[n], sr_[n], fmaf(-zi[n], si_[n], ub));
                si_[n] = fmaf(zr[n], si_[n], zi[n] * sr_[n]);
                sr_[n] = nr;
            }
        }
#pragma unroll
        for (int n = 0; n < NSTATE; ++n) { myT[2 * n] = sr_[n]; myT[2 * n + 1] = si_[n]; }
    }
    __syncthreads();

    // B-bwd suffix
    float Er[16] = {}, Ei[16] = {};
    for (int i = nch - 1; i > j; --i) {
        const float* T = &tls[(lr * nch + i) * 33];
#pragma unroll
        for (int n = 0; n < NSTATE; ++n) {
            float tr = T[2 * n], ti = T[2 * n + 1];
            float nr = fmaf(zCr[n], Er[n], fmaf(-zCi[n], Ei[n], tr));
            Ei[n] = fmaf(zCr[n], Ei[n], fmaf(zCi[n], Er[n], ti));
            Er[n] = nr;
        }
    }

    // C2: backward emit y_t = bf16(gelu(tmp + cb)) transposed
#pragma unroll 4
    for (int m = 0; m < CHUNK; ++m) {
        int idx = c0 + CHUNK - m;
        float ub = (idx < L) ? ur[idx] : 0.f;
        float cb0 = 0.f, cb1 = 0.f, cb2 = 0.f, cb3 = 0.f;
#pragma unroll
        for (int n = 0; n < NSTATE; ++n) {
            float nr = fmaf(zr[n], Er[n], fmaf(-zi[n], Ei[n], ub));
            Ei[n] = fmaf(zr[n], Ei[n], zi[n] * Er[n]);
            Er[n] = nr;
            float c = fmaf(w1r[n], Er[n], -w1i[n] * Ei[n]);
            if ((n & 3) == 0) cb0 += c; else if ((n & 3) == 1) cb1 += c;
            else if ((n & 3) == 2) cb2 += c; else cb3 += c;
        }
        int p = c0 + CHUNK - 1 - m;
        if ((p & (ds - 1)) == 0) {
            float v = trow[p / ds] + (cb0 + cb1) + (cb2 + cb3);
            float g = 0.5f * v * (1.0f + erff(v * 0.70710678118f));
            yt[((size_t)b * Lk + p / ds) * HDIM + h] = f2bf(g);
        }
    }
}

// ---------------------------------------------------------------------------
// LayerNorm over H of (B, H, Lk)
// ---------------------------------------------------------------------------
__global__ void __launch_bounds__(256) ln_kernel(
    const float* __restrict__ x, float* __restrict__ dst,
    const float* __restrict__ nw, const float* __restrict__ nb, int Lk)
{
    __shared__ float ss[16][17], qq[16][17], mus[16], rss[16];
    int tid = threadIdx.x;
    int lo = tid & 15, hg = tid >> 4;
    int b = blockIdx.y;
    int l = blockIdx.x * 16 + lo;
    const float* base = x + (size_t)b * HDIM * Lk + l;
    float s = 0.f, q = 0.f;
    for (int hh = hg; hh < HDIM; hh += 16) {
        float v = base[(size_t)hh * Lk];
        s += v; q = fmaf(v, v, q);
    }
    ss[hg][lo] = s; qq[hg][lo] = q;
    __syncthreads();
    if (hg == 0) {
        float S = 0.f, Q = 0.f;
#pragma unroll
        for (int t2 = 0; t2 < 16; ++t2) { S += ss[t2][lo]; Q += qq[t2][lo]; }
        float mu = S * (1.0f / HDIM);
        float var = Q * (1.0f / HDIM) - mu * mu;
        mus[lo] = mu; rss[lo] = rsqrtf(var + 1e-5f);
    }
    __syncthreads();
    float mu = mus[lo], rs = rss[lo];
    float* dbase = dst + (size_t)b * HDIM * Lk + l;
    for (int hh = hg; hh < HDIM; hh += 16) {
        float v = base[(size_t)hh * Lk];
        dbase[(size_t)hh * Lk] = (v - mu) * rs * nw[hh] + nb[hh];
    }
}

// ---------------------------------------------------------------------------
// Head: out[b,l,o] = sum_h u[b,h,l]*wout[h,o] + wb[o]  (f32)
// ---------------------------------------------------------------------------
__global__ void __launch_bounds__(256) head_kernel(
    const float* __restrict__ u, const float* __restrict__ wout,
    const float* __restrict__ wb, float* __restrict__ out, int Lk)
{
    __shared__ float wsh[64][40];
    int tid = threadIdx.x;
    int lt = tid & 63, og = tid >> 6;
    int b = blockIdx.y;
    int l = blockIdx.x * 64 + lt;
    float acc[10];
#pragma unroll
    for (int k = 0; k < 10; ++k) acc[k] = 0.f;
    for (int c0 = 0; c0 < HDIM; c0 += 64) {
        for (int p = tid; p < 64 * 38; p += 256) {
            int hh = p / 38, o = p - hh * 38;
            wsh[hh][o] = wout[(size_t)(c0 + hh) * 38 + o];
        }
        __syncthreads();
        for (int hh = 0; hh < 64; ++hh) {
            float uv = u[((size_t)b * HDIM + c0 + hh) * Lk + l];
#pragma unroll
            for (int k = 0; k < 10; ++k) {
                int o = og + 4 * k;
                if (o < 38) acc[k] = fmaf(uv, wsh[hh][o], acc[k]);
            }
        }
        __syncthreads();
    }
#pragma unroll
    for (int k = 0; k < 10; ++k) {
        int o = og + 4 * k;
        if (o < 38)
            out[((size_t)b * Lk + l) * 38 + o] = acc[k] + wb[o];
    }
}

// ---------------------------------------------------------------------------
extern "C" void kernel_launch(void* const* d_in, const int* in_sizes, int n_in,
                              void* d_out, int out_size, void* d_ws, size_t ws_size,
                              hipStream_t stream)
{
    (void)in_sizes; (void)n_in; (void)out_size; (void)ws_size;
    const float* x_raw      = (const float*)d_in[1];
    const float* enc_w1     = (const float*)d_in[3];
    const float* enc_b1     = (const float*)d_in[4];
    const float* enc_w2     = (const float*)d_in[5];
    const float* enc_b2     = (const float*)d_in[6];
    const float* log_dt     = (const float*)d_in[7];
    const float* log_A_real = (const float*)d_in[8];
    const float* A_imag     = (const float*)d_in[9];
    const float* C_ri       = (const float*)d_in[10];
    const float* Dp         = (const float*)d_in[11];
    const float* out_w      = (const float*)d_in[12];
    const float* out_b      = (const float*)d_in[13];
    const float* norm_w     = (const float*)d_in[14];
    const float* norm_b     = (const float*)d_in[15];
    const float* wout_w     = (const float*)d_in[16];
    const float* wout_b     = (const float*)d_in[17];

    char* ws = (char*)d_ws;
    // Region A (50331648 B): u buffer (B,H,L) f32
    // Region B (25165824 B): hbf during enc era; then y_t (front 12.58MB) + wslot (@+12582912)
    // Region C (25165824 B): w2t during enc era; then tmp (ssm) / xr (glu+ln)
    float* Abuf = (float*)ws;
    char*  Bb   = ws + 50331648;
    unsigned short* hbf   = (unsigned short*)Bb;
    unsigned short* ytb   = (unsigned short*)Bb;
    unsigned short* wslot = (unsigned short*)(Bb + 12582912);
    char*  Cb   = ws + 75497472;
    unsigned short* w2t = (unsigned short*)Cb;
    float* tmp = (float*)Cb;
    float* xr  = (float*)Cb;

    const int B = 8;

    w2t_kernel<<<288, 256, 0, stream>>>(enc_w2, w2t);
    hprep_kernel<<<6144, 256, 0, stream>>>(x_raw, enc_w1, enc_b1, hbf);
    enc_mfma_kernel<<<dim3(12, 128), 256, 0, stream>>>(w2t, hbf, enc_b2, Abuf);

    int L = 2048;
    for (int i = 0; i < 6; ++i) {
        int ds = (i <= 2) ? 2 : 1;
        int Lk = L / ds;
        int lognch = 31 - __builtin_clz(L / CHUNK);
        ssm_chunk_kernel<<<24 << lognch, 256, 0, stream>>>(
            Abuf, ytb, tmp,
            log_dt + (size_t)i * HDIM,
            log_A_real + (size_t)i * HDIM * NSTATE,
            A_imag + (size_t)i * HDIM * NSTATE,
            C_ri + (size_t)i * 2 * HDIM * NSTATE * 2,
            Dp + (size_t)i * HDIM, L, ds, lognch);
        wconv_kernel<<<576, 256, 0, stream>>>(
            out_w + (size_t)i * 1536 * HDIM, wslot, 1536 * 96);
        glu_mfma_kernel<<<dim3(12, Lk / 128, B), 256, 0, stream>>>(
            wslot, ytb, Abuf, out_b + (size_t)i * 1536, xr, Lk, ds);
        ln_kernel<<<dim3(Lk / 16, B), 256, 0, stream>>>(
            xr, Abuf, norm_w + (size_t)i * HDIM, norm_b + (size_t)i * HDIM, Lk);
        L = Lk;
    }

    head_kernel<<<dim3(L / 64, B), 256, 0, stream>>>(
        Abuf, wout_w, wout_b, (float*)d_out, L);
}

// Round 7
// 1349.896 us; speedup vs baseline: 2.7245x; 1.2588x over previous
//
#include <hip/hip_runtime.h>
#include <hip/hip_bf16.h>
#include <math.h>

#define HDIM 768
#define NSTATE 16

typedef __attribute__((ext_vector_type(8))) short bf16x8;
typedef __attribute__((ext_vector_type(4))) float f32x4;
typedef __attribute__((ext_vector_type(4))) unsigned int u32x4;

__device__ __forceinline__ unsigned short f2bf(float f) {
    union { float f; unsigned int u; } v; v.f = f;
    unsigned int r = v.u + 0x7fff + ((v.u >> 16) & 1);   // RNE
    return (unsigned short)(r >> 16);
}

// ---------------------------------------------------------------------------
// wconv: f32 -> bf16 flat copy (8 elems/thread)
// ---------------------------------------------------------------------------
__global__ void __launch_bounds__(256) wconv_kernel(
    const float* __restrict__ src, unsigned short* __restrict__ dst, int n8)
{
    int t = blockIdx.x * 256 + threadIdx.x;
    if (t >= n8) return;
    const float* s = src + (size_t)t * 8;
    float4 a = *(const float4*)s, b = *(const float4*)(s + 4);
    union { unsigned short us[8]; u32x4 v; } o;
    o.us[0] = f2bf(a.x); o.us[1] = f2bf(a.y); o.us[2] = f2bf(a.z); o.us[3] = f2bf(a.w);
    o.us[4] = f2bf(b.x); o.us[5] = f2bf(b.y); o.us[6] = f2bf(b.z); o.us[7] = f2bf(b.w);
    *(u32x4*)(dst + (size_t)t * 8) = o.v;
}

// ---------------------------------------------------------------------------
// w2t: transpose + convert enc_w2 (768k x 768j) -> (768j x 768k) bf16
// ---------------------------------------------------------------------------
__global__ void __launch_bounds__(256) w2t_kernel(
    const float* __restrict__ w2, unsigned short* __restrict__ w2t)
{
    int T = blockIdx.x * 256 + threadIdx.x;   // < 768*96
    int j = T / 96, kc = T - j * 96;
    union { unsigned short us[8]; u32x4 v; } o;
#pragma unroll
    for (int i = 0; i < 8; ++i)
        o.us[i] = f2bf(w2[(size_t)(kc * 8 + i) * HDIM + j]);
    *(u32x4*)(w2t + (size_t)j * HDIM + kc * 8) = o.v;
}

// ---------------------------------------------------------------------------
// hprep: h[r][k] = softsign(x_raw[r] @ w1[:,k] + b1[k]) -> bf16 (16384, 768)
// ---------------------------------------------------------------------------
__global__ void __launch_bounds__(256) hprep_kernel(
    const float* __restrict__ xraw, const float* __restrict__ w1,
    const float* __restrict__ b1, unsigned short* __restrict__ hbf)
{
    __shared__ float w1s[8 * HDIM];
    __shared__ float b1s[HDIM];
    int tid = threadIdx.x;
    for (int p = tid; p < 8 * HDIM; p += 256) w1s[p] = w1[p];
    for (int p = tid; p < HDIM; p += 256) b1s[p] = b1[p];
    __syncthreads();
    int T = blockIdx.x * 256 + tid;           // < 16384*96
    int r = T / 96, kc = T - r * 96;
    float4 xa = *(const float4*)(xraw + (size_t)r * 8);
    float4 xb = *(const float4*)(xraw + (size_t)r * 8 + 4);
    float xq[8] = {xa.x, xa.y, xa.z, xa.w, xb.x, xb.y, xb.z, xb.w};
    float acc[8];
#pragma unroll
    for (int i = 0; i < 8; ++i) acc[i] = b1s[kc * 8 + i];
#pragma unroll
    for (int q = 0; q < 8; ++q)
#pragma unroll
        for (int i = 0; i < 8; ++i)
            acc[i] = fmaf(xq[q], w1s[q * HDIM + kc * 8 + i], acc[i]);
    union { unsigned short us[8]; u32x4 v; } o;
#pragma unroll
    for (int i = 0; i < 8; ++i) {
        float h = acc[i] / (1.0f + fabsf(acc[i]));
        o.us[i] = f2bf(h);
    }
    *(u32x4*)(hbf + (size_t)r * HDIM + kc * 8) = o.v;
}

// ---------------------------------------------------------------------------
// enc_mfma: u0 (B,768,2048) f32 = w2t(768j,768k) @ hbf(16384r,768k)^T + b2
// ---------------------------------------------------------------------------
__global__ void __launch_bounds__(256) enc_mfma_kernel(
    const unsigned short* __restrict__ w2t,
    const unsigned short* __restrict__ hbf,
    const float* __restrict__ b2,
    float* __restrict__ u0)
{
    __shared__ unsigned short lds[2][192 * 64];
    int tid = threadIdx.x;
    int j0 = blockIdx.x * 64;
    int r0 = blockIdx.y * 128;
    int w = tid >> 6, lane = tid & 63;
    int wj = w >> 1, wl = w & 1;
    f32x4 acc[2][4];
    f32x4 zf = {0.f, 0.f, 0.f, 0.f};
#pragma unroll
    for (int dg = 0; dg < 2; ++dg)
#pragma unroll
        for (int cg = 0; cg < 4; ++cg) acc[dg][cg] = zf;

    u32x4 stg[6];
#define ENC_LOAD(kt) do { int k0_ = (kt) * 64; \
    _Pragma("unroll") for (int s = 0; s < 6; ++s) { \
        int c = s * 256 + tid; int row = c >> 3, m = c & 7; \
        const unsigned short* g = (row < 64) \
            ? (w2t + (size_t)(j0 + row) * HDIM + k0_ + m * 8) \
            : (hbf + (size_t)(r0 + row - 64) * HDIM + k0_ + m * 8); \
        stg[s] = *(const u32x4*)g; } } while (0)
#define ENC_WRITE(bi) do { \
    _Pragma("unroll") for (int s = 0; s < 6; ++s) { \
        int c = s * 256 + tid; int row = c >> 3, m = c & 7; \
        *(u32x4*)&lds[bi][row * 64 + 8 * (m ^ (row & 7))] = stg[s]; } } while (0)

    ENC_LOAD(0); ENC_WRITE(0);
    int cur = 0;
    for (int t = 0; t < 12; ++t) {
        __syncthreads();
        if (t < 11) ENC_LOAD(t + 1);
#pragma unroll
        for (int kh = 0; kh < 2; ++kh) {
            int kg = kh * 4 + (lane >> 4);
            bf16x8 af[2], bfr[4];
#pragma unroll
            for (int dg = 0; dg < 2; ++dg) {
                int rA = wj * 32 + dg * 16 + (lane & 15);
                af[dg] = *(bf16x8*)&lds[cur][rA * 64 + 8 * (kg ^ (rA & 7))];
            }
#pragma unroll
            for (int cg = 0; cg < 4; ++cg) {
                int rB = 64 + wl * 64 + cg * 16 + (lane & 15);
                bfr[cg] = *(bf16x8*)&lds[cur][rB * 64 + 8 * (kg ^ (rB & 7))];
            }
#pragma unroll
            for (int dg = 0; dg < 2; ++dg)
#pragma unroll
                for (int cg = 0; cg < 4; ++cg)
                    acc[dg][cg] = __builtin_amdgcn_mfma_f32_16x16x32_bf16(
                        af[dg], bfr[cg], acc[dg][cg], 0, 0, 0);
        }
        if (t < 11) ENC_WRITE(cur ^ 1);
        cur ^= 1;
    }
    int b = r0 >> 11;
    int l0 = r0 & 2047;
#pragma unroll
    for (int dg = 0; dg < 2; ++dg) {
        int j = j0 + wj * 32 + dg * 16 + ((lane >> 4) << 2);
#pragma unroll
        for (int cg = 0; cg < 4; ++cg) {
            int l = l0 + wl * 64 + cg * 16 + (lane & 15);
#pragma unroll
            for (int i = 0; i < 4; ++i)
                u0[((size_t)(b * HDIM + j + i)) * 2048 + l] = acc[dg][cg][i] + b2[j + i];
        }
    }
#undef ENC_LOAD
#undef ENC_WRITE
}

// ---------------------------------------------------------------------------
// glu_mfma: a = W[0:768]@Y, g = W[768:]@Y (bf16 MFMA, f32 acc);
//           xr = (a+ba)*sigmoid(g+bg) + u[:, ::ds]   out (B,768,Lk) f32
// ---------------------------------------------------------------------------
__global__ void __launch_bounds__(256) glu_mfma_kernel(
    const unsigned short* __restrict__ wbf,   // (1536, 768) bf16
    const unsigned short* __restrict__ yt,    // (B, Lk, 768) bf16
    const float* __restrict__ u,              // (B, 768, Lk*ds)
    const float* __restrict__ ob,             // (1536)
    float* __restrict__ xr,                   // (B, 768, Lk)
    int Lk, int ds)
{
    __shared__ unsigned short lds[2][256 * 64];
    int tid = threadIdx.x;
    int d0 = blockIdx.x * 64;
    int l0 = blockIdx.y * 128;
    int b  = blockIdx.z;
    int w = tid >> 6, lane = tid & 63;
    int wd = w >> 1, wl = w & 1;
    f32x4 accA[2][4], accG[2][4];
    f32x4 zf = {0.f, 0.f, 0.f, 0.f};
#pragma unroll
    for (int dg = 0; dg < 2; ++dg)
#pragma unroll
        for (int cg = 0; cg < 4; ++cg) { accA[dg][cg] = zf; accG[dg][cg] = zf; }

    u32x4 stg[8];
#define GLU_LOAD(kt) do { int k0_ = (kt) * 64; \
    _Pragma("unroll") for (int s = 0; s < 8; ++s) { \
        int c = s * 256 + tid; int row = c >> 3, m = c & 7; \
        const unsigned short* g; \
        if (row < 64)       g = wbf + (size_t)(d0 + row) * HDIM + k0_ + m * 8; \
        else if (row < 128) g = wbf + (size_t)(768 + d0 + row - 64) * HDIM + k0_ + m * 8; \
        else g = yt + ((size_t)b * Lk + l0 + row - 128) * HDIM + k0_ + m * 8; \
        stg[s] = *(const u32x4*)g; } } while (0)
#define GLU_WRITE(bi) do { \
    _Pragma("unroll") for (int s = 0; s < 8; ++s) { \
        int c = s * 256 + tid; int row = c >> 3, m = c & 7; \
        *(u32x4*)&lds[bi][row * 64 + 8 * (m ^ (row & 7))] = stg[s]; } } while (0)

    GLU_LOAD(0); GLU_WRITE(0);
    int cur = 0;
    for (int t = 0; t < 12; ++t) {
        __syncthreads();
        if (t < 11) GLU_LOAD(t + 1);
#pragma unroll
        for (int kh = 0; kh < 2; ++kh) {
            int kg = kh * 4 + (lane >> 4);
            bf16x8 aa[2], ag[2], bfr[4];
#pragma unroll
            for (int dg = 0; dg < 2; ++dg) {
                int rA = wd * 32 + dg * 16 + (lane & 15);
                aa[dg] = *(bf16x8*)&lds[cur][rA * 64 + 8 * (kg ^ (rA & 7))];
                int rG = 64 + rA;
                ag[dg] = *(bf16x8*)&lds[cur][rG * 64 + 8 * (kg ^ (rG & 7))];
            }
#pragma unroll
            for (int cg = 0; cg < 4; ++cg) {
                int rB = 128 + wl * 64 + cg * 16 + (lane & 15);
                bfr[cg] = *(bf16x8*)&lds[cur][rB * 64 + 8 * (kg ^ (rB & 7))];
            }
#pragma unroll
            for (int dg = 0; dg < 2; ++dg)
#pragma unroll
                for (int cg = 0; cg < 4; ++cg) {
                    accA[dg][cg] = __builtin_amdgcn_mfma_f32_16x16x32_bf16(
                        aa[dg], bfr[cg], accA[dg][cg], 0, 0, 0);
                    accG[dg][cg] = __builtin_amdgcn_mfma_f32_16x16x32_bf16(
                        ag[dg], bfr[cg], accG[dg][cg], 0, 0, 0);
                }
        }
        if (t < 11) GLU_WRITE(cur ^ 1);
        cur ^= 1;
    }
    size_t L = (size_t)Lk * ds;
#pragma unroll
    for (int dg = 0; dg < 2; ++dg) {
        int d = d0 + wd * 32 + dg * 16 + ((lane >> 4) << 2);
#pragma unroll
        for (int cg = 0; cg < 4; ++cg) {
            int l = l0 + wl * 64 + cg * 16 + (lane & 15);
#pragma unroll
            for (int i = 0; i < 4; ++i) {
                float a = accA[dg][cg][i] + ob[d + i];
                float g = accG[dg][cg][i] + ob[d + i + 768];
                float sg = 1.0f / (1.0f + expf(-g));
                float res = u[((size_t)b * HDIM + d + i) * L + (size_t)l * ds];
                xr[((size_t)b * HDIM + d + i) * Lk + l] = fmaf(a, sg, res);
            }
        }
    }
#undef GLU_LOAD
#undef GLU_WRITE
}

// ---------------------------------------------------------------------------
// SSM, chunk-parallel, 2-way state split. CHUNK=32.
// thread = (row, chunk j, state-half sh): owns states n = sh*8..sh*8+7.
// tid = lr*(2*nch) + j*2 + sh  => sh=tid&1, j=(tid>>1)&(nch-1), lr=tid>>(1+lognch)
// Partner lane tid^1 holds the other 8 states of the same (row, chunk).
// Phases: A1 fwd-local->LDS | B-fwd prefix | C1 emit cf (regs) |
//         A2 bwd-local->LDS | B-bwd suffix | C2 emit y=cf+cb (shfl-paired), f32 row-major.
// LDS: per-thread 8 complex states as 4 float4, phys = slot*4 + (q ^ (slot&3)).
// ---------------------------------------------------------------------------
template<int DS>
__global__ void __launch_bounds__(256) ssm_split_kernel(
    const float* __restrict__ u,          // (6144, L)
    float* __restrict__ yout,             // (6144, L/DS) f32, gelu'd
    const float* __restrict__ log_dt,
    const float* __restrict__ log_A_real,
    const float* __restrict__ A_imag,
    const float* __restrict__ C_ri,
    const float* __restrict__ Dp,
    int L, int lognch)
{
    __shared__ float4 tlsv[1024];          // 256 slots * 4
    const int KEPT = 32 / DS;
    int tid = threadIdx.x;
    int nch = 1 << lognch;
    int sh  = tid & 1;
    int j   = (tid >> 1) & (nch - 1);
    int rpb = 128 >> lognch;
    int lr  = tid >> (1 + lognch);
    int row = blockIdx.x * rpb + lr;
    int b   = row / HDIM;
    int h   = row - b * HDIM;
    int c0  = j * 32;
    const float* ur = u + (size_t)row * L;
    int Lk = L / DS;

    // constants for my 8 states
    float zr[8], zi[8], zCr[8], zCi[8], w0r[8], w0i[8], w1r[8], w1i[8];
    float dt = expf(log_dt[h]);
#pragma unroll
    for (int k = 0; k < 8; ++k) {
        int n = sh * 8 + k;
        float Ar = -expf(log_A_real[h * NSTATE + n]);
        float Ai = A_imag[h * NSTATE + n];
        float er = expf(dt * Ar);
        float th = dt * Ai;
        zr[k] = er * cosf(th); zi[k] = er * sinf(th);
        float pr = zr[k], pi = zi[k];          // zC = z^32 via 5 squarings
#pragma unroll
        for (int s = 0; s < 5; ++s) {
            float t2 = pr * pr - pi * pi;
            pi = 2.f * pr * pi; pr = t2;
        }
        zCr[k] = pr; zCi[k] = pi;
        float den = Ar * Ar + Ai * Ai;
        float t0 = zr[k] - 1.0f;
        float dBr = (t0 * Ar + zi[k] * Ai) / den;
        float dBi = (zi[k] * Ar - t0 * Ai) / den;
        float C0r = C_ri[((0 * HDIM + h) * NSTATE + n) * 2 + 0];
        float C0i = C_ri[((0 * HDIM + h) * NSTATE + n) * 2 + 1];
        float C1r = C_ri[((1 * HDIM + h) * NSTATE + n) * 2 + 0];
        float C1i = C_ri[((1 * HDIM + h) * NSTATE + n) * 2 + 1];
        w0r[k] = 2.0f * (C0r * dBr - C0i * dBi);
        w0i[k] = 2.0f * (C0r * dBi + C0i * dBr);
        w1r[k] = 2.0f * (C1r * dBr - C1i * dBi);
        w1i[k] = 2.0f * (C1r * dBi + C1i * dBr);
    }
    int myslot = (j * rpb + lr) * 2 + sh;

    // --- A1: forward local end-state ---
    {
        float sr_[8] = {}, si_[8] = {};
#pragma unroll 8
        for (int i = 0; i < 32; ++i) {
            float uf = ur[c0 + i];
#pragma unroll
            for (int k = 0; k < 8; ++k) {
                float nr = fmaf(zr[k], sr_[k], fmaf(-zi[k], si_[k], uf));
                si_[k] = fmaf(zr[k], si_[k], zi[k] * sr_[k]);
                sr_[k] = nr;
            }
        }
#pragma unroll
        for (int q = 0; q < 4; ++q)
            tlsv[myslot * 4 + (q ^ (myslot & 3))] =
                make_float4(sr_[2 * q], si_[2 * q], sr_[2 * q + 1], si_[2 * q + 1]);
    }
    __syncthreads();

    // --- B-fwd prefix: S = sum_{i<j} zC^{j-1-i} T_i ---
    float Sr[8] = {}, Si[8] = {};
    for (int i = 0; i < j; ++i) {
        int sl = (i * rpb + lr) * 2 + sh;
        float4 t0v = tlsv[sl * 4 + (0 ^ (sl & 3))];
        float4 t1v = tlsv[sl * 4 + (1 ^ (sl & 3))];
        float4 t2v = tlsv[sl * 4 + (2 ^ (sl & 3))];
        float4 t3v = tlsv[sl * 4 + (3 ^ (sl & 3))];
        float tr[8] = {t0v.x, t0v.z, t1v.x, t1v.z, t2v.x, t2v.z, t3v.x, t3v.z};
        float ti[8] = {t0v.y, t0v.w, t1v.y, t1v.w, t2v.y, t2v.w, t3v.y, t3v.w};
#pragma unroll
        for (int k = 0; k < 8; ++k) {
            float nr = fmaf(zCr[k], Sr[k], fmaf(-zCi[k], Si[k], tr[k]));
            Si[k] = fmaf(zCr[k], Si[k], fmaf(zCi[k], Sr[k], ti[k]));
            Sr[k] = nr;
        }
    }

    // --- C1: forward emit into registers ---
    float Dh_eff = (sh == 0) ? Dp[h] : 0.0f;
    float cf[KEPT];
#pragma unroll
    for (int i = 0; i < 32; ++i) {
        float uf = ur[c0 + i];
        float ca = 0.f, cb = 0.f;
#pragma unroll
        for (int k = 0; k < 8; ++k) {
            float nr = fmaf(zr[k], Sr[k], fmaf(-zi[k], Si[k], uf));
            Si[k] = fmaf(zr[k], Si[k], zi[k] * Sr[k]);
            Sr[k] = nr;
            float c = fmaf(w0r[k], Sr[k], -w0i[k] * Si[k]);
            if (k & 1) cb += c; else ca += c;
        }
        if ((i & (DS - 1)) == 0)
            cf[i / DS] = fmaf(Dh_eff, uf, ca + cb);
    }
    __syncthreads();   // all B-fwd reads complete before A2 overwrites

    // --- A2: backward local end-state ---
    {
        float sr_[8] = {}, si_[8] = {};
#pragma unroll 8
        for (int m = 0; m < 32; ++m) {
            int idx = c0 + 32 - m;
            float ub = (idx < L) ? ur[idx] : 0.f;
#pragma unroll
            for (int k = 0; k < 8; ++k) {
                float nr = fmaf(zr[k], sr_[k], fmaf(-zi[k], si_[k], ub));
                si_[k] = fmaf(zr[k], si_[k], zi[k] * sr_[k]);
                sr_[k] = nr;
            }
        }
#pragma unroll
        for (int q = 0; q < 4; ++q)
            tlsv[myslot * 4 + (q ^ (myslot & 3))] =
                make_float4(sr_[2 * q], si_[2 * q], sr_[2 * q + 1], si_[2 * q + 1]);
    }
    __syncthreads();

    // --- B-bwd suffix: E = sum_{i>j} zC^{i-j-1} T_i ---
    float Er[8] = {}, Ei[8] = {};
    for (int i = nch - 1; i > j; --i) {
        int sl = (i * rpb + lr) * 2 + sh;
        float4 t0v = tlsv[sl * 4 + (0 ^ (sl & 3))];
        float4 t1v = tlsv[sl * 4 + (1 ^ (sl & 3))];
        float4 t2v = tlsv[sl * 4 + (2 ^ (sl & 3))];
        float4 t3v = tlsv[sl * 4 + (3 ^ (sl & 3))];
        float tr[8] = {t0v.x, t0v.z, t1v.x, t1v.z, t2v.x, t2v.z, t3v.x, t3v.z};
        float ti[8] = {t0v.y, t0v.w, t1v.y, t1v.w, t2v.y, t2v.w, t3v.y, t3v.w};
#pragma unroll
        for (int k = 0; k < 8; ++k) {
            float nr = fmaf(zCr[k], Er[k], fmaf(-zCi[k], Ei[k], tr[k]));
            Ei[k] = fmaf(zCr[k], Ei[k], fmaf(zCi[k], Er[k], ti[k]));
            Er[k] = nr;
        }
    }

    // --- C2: backward emit, pair-sum via shfl, store f32 row-major ---
    float* yr = yout + (size_t)row * Lk + (c0 / DS);
#pragma unroll
    for (int m = 0; m < 32; ++m) {
        int idx = c0 + 32 - m;
        float ub = (idx < L) ? ur[idx] : 0.f;
#pragma unroll
        for (int k = 0; k < 8; ++k) {
            float nr = fmaf(zr[k], Er[k], fmaf(-zi[k], Ei[k], ub));
            Ei[k] = fmaf(zr[k], Ei[k], zi[k] * Er[k]);
            Er[k] = nr;
        }
        if (((31 - m) & (DS - 1)) == 0) {
            float ca = 0.f, cb = 0.f;
#pragma unroll
            for (int k = 0; k < 8; ++k) {
                float c = fmaf(w1r[k], Er[k], -w1i[k] * Ei[k]);
                if (k & 1) cb += c; else ca += c;
            }
            int k2 = (31 - m) / DS;
            float v = cf[k2] + ca + cb;
            v += __shfl_xor(v, 1, 64);
            if (sh == 0) {
                float g = 0.5f * v * (1.0f + erff(v * 0.70710678118f));
                yr[k2] = g;
            }
        }
    }
}

// ---------------------------------------------------------------------------
// ytr: transpose (6144 rows, Lk) f32 -> (B, Lk, 768) bf16, LDS-tiled 64x64
// ---------------------------------------------------------------------------
__global__ void __launch_bounds__(256) ytr_kernel(
    const float* __restrict__ yf, unsigned short* __restrict__ yt, int Lk)
{
    __shared__ float tile[64][65];
    int tid = threadIdx.x;
    int p0 = blockIdx.x * 64;
    int r0 = blockIdx.y * 64;
    int tp = tid & 63, th = tid >> 6;
#pragma unroll
    for (int s = 0; s < 16; ++s) {
        int hh = th * 16 + s;
        tile[hh][tp] = yf[(size_t)(r0 + hh) * Lk + p0 + tp];
    }
    __syncthreads();
    int b = r0 / HDIM, h0 = r0 - b * HDIM;
#pragma unroll
    for (int s = 0; s < 16; ++s) {
        int pp = th * 16 + s;
        yt[((size_t)b * Lk + p0 + pp) * HDIM + h0 + tp] = f2bf(tile[tp][pp]);
    }
}

// ---------------------------------------------------------------------------
// LayerNorm over H of (B, H, Lk)
// ---------------------------------------------------------------------------
__global__ void __launch_bounds__(256) ln_kernel(
    const float* __restrict__ x, float* __restrict__ dst,
    const float* __restrict__ nw, const float* __restrict__ nb, int Lk)
{
    __shared__ float ss[16][17], qq[16][17], mus[16], rss[16];
    int tid = threadIdx.x;
    int lo = tid & 15, hg = tid >> 4;
    int b = blockIdx.y;
    int l = blockIdx.x * 16 + lo;
    const float* base = x + (size_t)b * HDIM * Lk + l;
    float s = 0.f, q = 0.f;
    for (int hh = hg; hh < HDIM; hh += 16) {
        float v = base[(size_t)hh * Lk];
        s += v; q = fmaf(v, v, q);
    }
    ss[hg][lo] = s; qq[hg][lo] = q;
    __syncthreads();
    if (hg == 0) {
        float S = 0.f, Q = 0.f;
#pragma unroll
        for (int t2 = 0; t2 < 16; ++t2) { S += ss[t2][lo]; Q += qq[t2][lo]; }
        float mu = S * (1.0f / HDIM);
        float var = Q * (1.0f / HDIM) - mu * mu;
        mus[lo] = mu; rss[lo] = rsqrtf(var + 1e-5f);
    }
    __syncthreads();
    float mu = mus[lo], rs = rss[lo];
    float* dbase = dst + (size_t)b * HDIM * Lk + l;
    for (int hh = hg; hh < HDIM; hh += 16) {
        float v = base[(size_t)hh * Lk];
        dbase[(size_t)hh * Lk] = (v - mu) * rs * nw[hh] + nb[hh];
    }
}

// ---------------------------------------------------------------------------
// Head: out[b,l,o] = sum_h u[b,h,l]*wout[h,o] + wb[o]  (f32)
// ---------------------------------------------------------------------------
__global__ void __launch_bounds__(256) head_kernel(
    const float* __restrict__ u, const float* __restrict__ wout,
    const float* __restrict__ wb, float* __restrict__ out, int Lk)
{
    __shared__ float wsh[64][40];
    int tid = threadIdx.x;
    int lt = tid & 63, og = tid >> 6;
    int b = blockIdx.y;
    int l = blockIdx.x * 64 + lt;
    float acc[10];
#pragma unroll
    for (int k = 0; k < 10; ++k) acc[k] = 0.f;
    for (int c0 = 0; c0 < HDIM; c0 += 64) {
        for (int p = tid; p < 64 * 38; p += 256) {
            int hh = p / 38, o = p - hh * 38;
            wsh[hh][o] = wout[(size_t)(c0 + hh) * 38 + o];
        }
        __syncthreads();
        for (int hh = 0; hh < 64; ++hh) {
            float uv = u[((size_t)b * HDIM + c0 + hh) * Lk + l];
#pragma unroll
            for (int k = 0; k < 10; ++k) {
                int o = og + 4 * k;
                if (o < 38) acc[k] = fmaf(uv, wsh[hh][o], acc[k]);
            }
        }
        __syncthreads();
    }
#pragma unroll
    for (int k = 0; k < 10; ++k) {
        int o = og + 4 * k;
        if (o < 38)
            out[((size_t)b * Lk + l) * 38 + o] = acc[k] + wb[o];
    }
}

// ---------------------------------------------------------------------------
extern "C" void kernel_launch(void* const* d_in, const int* in_sizes, int n_in,
                              void* d_out, int out_size, void* d_ws, size_t ws_size,
                              hipStream_t stream)
{
    (void)in_sizes; (void)n_in; (void)out_size; (void)ws_size;
    const float* x_raw      = (const float*)d_in[1];
    const float* enc_w1     = (const float*)d_in[3];
    const float* enc_b1     = (const float*)d_in[4];
    const float* enc_w2     = (const float*)d_in[5];
    const float* enc_b2     = (const float*)d_in[6];
    const float* log_dt     = (const float*)d_in[7];
    const float* log_A_real = (const float*)d_in[8];
    const float* A_imag     = (const float*)d_in[9];
    const float* C_ri       = (const float*)d_in[10];
    const float* Dp         = (const float*)d_in[11];
    const float* out_w      = (const float*)d_in[12];
    const float* out_b      = (const float*)d_in[13];
    const float* norm_w     = (const float*)d_in[14];
    const float* norm_b     = (const float*)d_in[15];
    const float* wout_w     = (const float*)d_in[16];
    const float* wout_b     = (const float*)d_in[17];

    char* ws = (char*)d_ws;
    // A (50331648): u (B,H,L) f32
    // B (25165824): hbf (enc era); then ytb (12.58 MB) + wslot (@+12582912)
    // C (25165824): w2t (enc era); then yf32 (ssm out) / xr (glu out, ln in)
    float* Abuf = (float*)ws;
    char*  Bb   = ws + 50331648;
    unsigned short* hbf   = (unsigned short*)Bb;
    unsigned short* ytb   = (unsigned short*)Bb;
    unsigned short* wslot = (unsigned short*)(Bb + 12582912);
    char*  Cb   = ws + 75497472;
    unsigned short* w2t = (unsigned short*)Cb;
    float* yf = (float*)Cb;
    float* xr = (float*)Cb;

    const int B = 8;

    w2t_kernel<<<288, 256, 0, stream>>>(enc_w2, w2t);
    hprep_kernel<<<6144, 256, 0, stream>>>(x_raw, enc_w1, enc_b1, hbf);
    enc_mfma_kernel<<<dim3(12, 128), 256, 0, stream>>>(w2t, hbf, enc_b2, Abuf);

    int L = 2048;
    for (int i = 0; i < 6; ++i) {
        int ds = (i <= 2) ? 2 : 1;
        int Lk = L / ds;
        int lognch = 31 - __builtin_clz(L / 32);     // chunks of 32
        int rpb = 128 >> lognch;
        int nblk = 6144 / rpb;
        if (ds == 2)
            ssm_split_kernel<2><<<nblk, 256, 0, stream>>>(
                Abuf, yf,
                log_dt + (size_t)i * HDIM,
                log_A_real + (size_t)i * HDIM * NSTATE,
                A_imag + (size_t)i * HDIM * NSTATE,
                C_ri + (size_t)i * 2 * HDIM * NSTATE * 2,
                Dp + (size_t)i * HDIM, L, lognch);
        else
            ssm_split_kernel<1><<<nblk, 256, 0, stream>>>(
                Abuf, yf,
                log_dt + (size_t)i * HDIM,
                log_A_real + (size_t)i * HDIM * NSTATE,
                A_imag + (size_t)i * HDIM * NSTATE,
                C_ri + (size_t)i * 2 * HDIM * NSTATE * 2,
                Dp + (size_t)i * HDIM, L, lognch);
        ytr_kernel<<<dim3(Lk / 64, 96), 256, 0, stream>>>(yf, ytb, Lk);
        wconv_kernel<<<576, 256, 0, stream>>>(
            out_w + (size_t)i * 1536 * HDIM, wslot, 1536 * 96);
        glu_mfma_kernel<<<dim3(12, Lk / 128, B), 256, 0, stream>>>(
            wslot, ytb, Abuf, out_b + (size_t)i * 1536, xr, Lk, ds);
        ln_kernel<<<dim3(Lk / 16, B), 256, 0, stream>>>(
            xr, Abuf, norm_w + (size_t)i * HDIM, norm_b + (size_t)i * HDIM, Lk);
        L = Lk;
    }

    head_kernel<<<dim3(L / 64, B), 256, 0, stream>>>(
        Abuf, wout_w, wout_b, (float*)d_out, L);
}

// Round 8
// 1243.061 us; speedup vs baseline: 2.9587x; 1.0859x over previous
//
#include <hip/hip_runtime.h>
#include <hip/hip_bf16.h>
#include <math.h>

#define HDIM 768
#define NSTATE 16

typedef __attribute__((ext_vector_type(8))) short bf16x8;
typedef __attribute__((ext_vector_type(4))) float f32x4;
typedef __attribute__((ext_vector_type(4))) unsigned int u32x4;

__device__ __forceinline__ unsigned short f2bf(float f) {
    union { float f; unsigned int u; } v; v.f = f;
    unsigned int r = v.u + 0x7fff + ((v.u >> 16) & 1);   // RNE
    return (unsigned short)(r >> 16);
}

// ---------------------------------------------------------------------------
// wconv: f32 -> bf16 flat copy (8 elems/thread)
// ---------------------------------------------------------------------------
__global__ void __launch_bounds__(256) wconv_kernel(
    const float* __restrict__ src, unsigned short* __restrict__ dst, int n8)
{
    int t = blockIdx.x * 256 + threadIdx.x;
    if (t >= n8) return;
    const float* s = src + (size_t)t * 8;
    float4 a = *(const float4*)s, b = *(const float4*)(s + 4);
    union { unsigned short us[8]; u32x4 v; } o;
    o.us[0] = f2bf(a.x); o.us[1] = f2bf(a.y); o.us[2] = f2bf(a.z); o.us[3] = f2bf(a.w);
    o.us[4] = f2bf(b.x); o.us[5] = f2bf(b.y); o.us[6] = f2bf(b.z); o.us[7] = f2bf(b.w);
    *(u32x4*)(dst + (size_t)t * 8) = o.v;
}

// ---------------------------------------------------------------------------
// w2t: transpose + convert enc_w2 (768k x 768j) -> (768j x 768k) bf16
// ---------------------------------------------------------------------------
__global__ void __launch_bounds__(256) w2t_kernel(
    const float* __restrict__ w2, unsigned short* __restrict__ w2t)
{
    int T = blockIdx.x * 256 + threadIdx.x;   // < 768*96
    int j = T / 96, kc = T - j * 96;
    union { unsigned short us[8]; u32x4 v; } o;
#pragma unroll
    for (int i = 0; i < 8; ++i)
        o.us[i] = f2bf(w2[(size_t)(kc * 8 + i) * HDIM + j]);
    *(u32x4*)(w2t + (size_t)j * HDIM + kc * 8) = o.v;
}

// ---------------------------------------------------------------------------
// hprep: h[r][k] = softsign(x_raw[r] @ w1[:,k] + b1[k]) -> bf16 (16384, 768)
// ---------------------------------------------------------------------------
__global__ void __launch_bounds__(256) hprep_kernel(
    const float* __restrict__ xraw, const float* __restrict__ w1,
    const float* __restrict__ b1, unsigned short* __restrict__ hbf)
{
    __shared__ float w1s[8 * HDIM];
    __shared__ float b1s[HDIM];
    int tid = threadIdx.x;
    for (int p = tid; p < 8 * HDIM; p += 256) w1s[p] = w1[p];
    for (int p = tid; p < HDIM; p += 256) b1s[p] = b1[p];
    __syncthreads();
    int T = blockIdx.x * 256 + tid;           // < 16384*96
    int r = T / 96, kc = T - r * 96;
    float4 xa = *(const float4*)(xraw + (size_t)r * 8);
    float4 xb = *(const float4*)(xraw + (size_t)r * 8 + 4);
    float xq[8] = {xa.x, xa.y, xa.z, xa.w, xb.x, xb.y, xb.z, xb.w};
    float acc[8];
#pragma unroll
    for (int i = 0; i < 8; ++i) acc[i] = b1s[kc * 8 + i];
#pragma unroll
    for (int q = 0; q < 8; ++q)
#pragma unroll
        for (int i = 0; i < 8; ++i)
            acc[i] = fmaf(xq[q], w1s[q * HDIM + kc * 8 + i], acc[i]);
    union { unsigned short us[8]; u32x4 v; } o;
#pragma unroll
    for (int i = 0; i < 8; ++i) {
        float h = acc[i] / (1.0f + fabsf(acc[i]));
        o.us[i] = f2bf(h);
    }
    *(u32x4*)(hbf + (size_t)r * HDIM + kc * 8) = o.v;
}

// ---------------------------------------------------------------------------
// enc_mfma: u0 (B,768,2048) f32 = w2t(768j,768k) @ hbf(16384r,768k)^T + b2
// ---------------------------------------------------------------------------
__global__ void __launch_bounds__(256) enc_mfma_kernel(
    const unsigned short* __restrict__ w2t,
    const unsigned short* __restrict__ hbf,
    const float* __restrict__ b2,
    float* __restrict__ u0)
{
    __shared__ unsigned short lds[2][192 * 64];
    int tid = threadIdx.x;
    int j0 = blockIdx.x * 64;
    int r0 = blockIdx.y * 128;
    int w = tid >> 6, lane = tid & 63;
    int wj = w >> 1, wl = w & 1;
    f32x4 acc[2][4];
    f32x4 zf = {0.f, 0.f, 0.f, 0.f};
#pragma unroll
    for (int dg = 0; dg < 2; ++dg)
#pragma unroll
        for (int cg = 0; cg < 4; ++cg) acc[dg][cg] = zf;

    u32x4 stg[6];
#define ENC_LOAD(kt) do { int k0_ = (kt) * 64; \
    _Pragma("unroll") for (int s = 0; s < 6; ++s) { \
        int c = s * 256 + tid; int row = c >> 3, m = c & 7; \
        const unsigned short* g = (row < 64) \
            ? (w2t + (size_t)(j0 + row) * HDIM + k0_ + m * 8) \
            : (hbf + (size_t)(r0 + row - 64) * HDIM + k0_ + m * 8); \
        stg[s] = *(const u32x4*)g; } } while (0)
#define ENC_WRITE(bi) do { \
    _Pragma("unroll") for (int s = 0; s < 6; ++s) { \
        int c = s * 256 + tid; int row = c >> 3, m = c & 7; \
        *(u32x4*)&lds[bi][row * 64 + 8 * (m ^ (row & 7))] = stg[s]; } } while (0)

    ENC_LOAD(0); ENC_WRITE(0);
    int cur = 0;
    for (int t = 0; t < 12; ++t) {
        __syncthreads();
        if (t < 11) ENC_LOAD(t + 1);
#pragma unroll
        for (int kh = 0; kh < 2; ++kh) {
            int kg = kh * 4 + (lane >> 4);
            bf16x8 af[2], bfr[4];
#pragma unroll
            for (int dg = 0; dg < 2; ++dg) {
                int rA = wj * 32 + dg * 16 + (lane & 15);
                af[dg] = *(bf16x8*)&lds[cur][rA * 64 + 8 * (kg ^ (rA & 7))];
            }
#pragma unroll
            for (int cg = 0; cg < 4; ++cg) {
                int rB = 64 + wl * 64 + cg * 16 + (lane & 15);
                bfr[cg] = *(bf16x8*)&lds[cur][rB * 64 + 8 * (kg ^ (rB & 7))];
            }
#pragma unroll
            for (int dg = 0; dg < 2; ++dg)
#pragma unroll
                for (int cg = 0; cg < 4; ++cg)
                    acc[dg][cg] = __builtin_amdgcn_mfma_f32_16x16x32_bf16(
                        af[dg], bfr[cg], acc[dg][cg], 0, 0, 0);
        }
        if (t < 11) ENC_WRITE(cur ^ 1);
        cur ^= 1;
    }
    int b = r0 >> 11;
    int l0 = r0 & 2047;
#pragma unroll
    for (int dg = 0; dg < 2; ++dg) {
        int j = j0 + wj * 32 + dg * 16 + ((lane >> 4) << 2);
#pragma unroll
        for (int cg = 0; cg < 4; ++cg) {
            int l = l0 + wl * 64 + cg * 16 + (lane & 15);
#pragma unroll
            for (int i = 0; i < 4; ++i)
                u0[((size_t)(b * HDIM + j + i)) * 2048 + l] = acc[dg][cg][i] + b2[j + i];
        }
    }
#undef ENC_LOAD
#undef ENC_WRITE
}

// ---------------------------------------------------------------------------
// glu_mfma: a = W[0:768]@Y, g = W[768:]@Y (bf16 MFMA, f32 acc);
//           xr = (a+ba)*sigmoid(g+bg) + u[:, ::ds]   out (B,768,Lk) f32
// ---------------------------------------------------------------------------
__global__ void __launch_bounds__(256) glu_mfma_kernel(
    const unsigned short* __restrict__ wbf,   // (1536, 768) bf16
    const unsigned short* __restrict__ yt,    // (B, Lk, 768) bf16
    const float* __restrict__ u,              // (B, 768, Lk*ds)
    const float* __restrict__ ob,             // (1536)
    float* __restrict__ xr,                   // (B, 768, Lk)
    int Lk, int ds)
{
    __shared__ unsigned short lds[2][256 * 64];
    int tid = threadIdx.x;
    int d0 = blockIdx.x * 64;
    int l0 = blockIdx.y * 128;
    int b  = blockIdx.z;
    int w = tid >> 6, lane = tid & 63;
    int wd = w >> 1, wl = w & 1;
    f32x4 accA[2][4], accG[2][4];
    f32x4 zf = {0.f, 0.f, 0.f, 0.f};
#pragma unroll
    for (int dg = 0; dg < 2; ++dg)
#pragma unroll
        for (int cg = 0; cg < 4; ++cg) { accA[dg][cg] = zf; accG[dg][cg] = zf; }

    u32x4 stg[8];
#define GLU_LOAD(kt) do { int k0_ = (kt) * 64; \
    _Pragma("unroll") for (int s = 0; s < 8; ++s) { \
        int c = s * 256 + tid; int row = c >> 3, m = c & 7; \
        const unsigned short* g; \
        if (row < 64)       g = wbf + (size_t)(d0 + row) * HDIM + k0_ + m * 8; \
        else if (row < 128) g = wbf + (size_t)(768 + d0 + row - 64) * HDIM + k0_ + m * 8; \
        else g = yt + ((size_t)b * Lk + l0 + row - 128) * HDIM + k0_ + m * 8; \
        stg[s] = *(const u32x4*)g; } } while (0)
#define GLU_WRITE(bi) do { \
    _Pragma("unroll") for (int s = 0; s < 8; ++s) { \
        int c = s * 256 + tid; int row = c >> 3, m = c & 7; \
        *(u32x4*)&lds[bi][row * 64 + 8 * (m ^ (row & 7))] = stg[s]; } } while (0)

    GLU_LOAD(0); GLU_WRITE(0);
    int cur = 0;
    for (int t = 0; t < 12; ++t) {
        __syncthreads();
        if (t < 11) GLU_LOAD(t + 1);
#pragma unroll
        for (int kh = 0; kh < 2; ++kh) {
            int kg = kh * 4 + (lane >> 4);
            bf16x8 aa[2], ag[2], bfr[4];
#pragma unroll
            for (int dg = 0; dg < 2; ++dg) {
                int rA = wd * 32 + dg * 16 + (lane & 15);
                aa[dg] = *(bf16x8*)&lds[cur][rA * 64 + 8 * (kg ^ (rA & 7))];
                int rG = 64 + rA;
                ag[dg] = *(bf16x8*)&lds[cur][rG * 64 + 8 * (kg ^ (rG & 7))];
            }
#pragma unroll
            for (int cg = 0; cg < 4; ++cg) {
                int rB = 128 + wl * 64 + cg * 16 + (lane & 15);
                bfr[cg] = *(bf16x8*)&lds[cur][rB * 64 + 8 * (kg ^ (rB & 7))];
            }
#pragma unroll
            for (int dg = 0; dg < 2; ++dg)
#pragma unroll
                for (int cg = 0; cg < 4; ++cg) {
                    accA[dg][cg] = __builtin_amdgcn_mfma_f32_16x16x32_bf16(
                        aa[dg], bfr[cg], accA[dg][cg], 0, 0, 0);
                    accG[dg][cg] = __builtin_amdgcn_mfma_f32_16x16x32_bf16(
                        ag[dg], bfr[cg], accG[dg][cg], 0, 0, 0);
                }
        }
        if (t < 11) GLU_WRITE(cur ^ 1);
        cur ^= 1;
    }
    size_t L = (size_t)Lk * ds;
#pragma unroll
    for (int dg = 0; dg < 2; ++dg) {
        int d = d0 + wd * 32 + dg * 16 + ((lane >> 4) << 2);
#pragma unroll
        for (int cg = 0; cg < 4; ++cg) {
            int l = l0 + wl * 64 + cg * 16 + (lane & 15);
#pragma unroll
            for (int i = 0; i < 4; ++i) {
                float a = accA[dg][cg][i] + ob[d + i];
                float g = accG[dg][cg][i] + ob[d + i + 768];
                float sg = 1.0f / (1.0f + expf(-g));
                float res = u[((size_t)b * HDIM + d + i) * L + (size_t)l * ds];
                xr[((size_t)b * HDIM + d + i) * Lk + l] = fmaf(a, sg, res);
            }
        }
    }
#undef GLU_LOAD
#undef GLU_WRITE
}

// ---------------------------------------------------------------------------
// SSM, chunk-parallel, 2-way state split. CHUNK=32. (unchanged from R7)
// ---------------------------------------------------------------------------
template<int DS>
__global__ void __launch_bounds__(256) ssm_split_kernel(
    const float* __restrict__ u,          // (6144, L)
    float* __restrict__ yout,             // (6144, L/DS) f32, gelu'd
    const float* __restrict__ log_dt,
    const float* __restrict__ log_A_real,
    const float* __restrict__ A_imag,
    const float* __restrict__ C_ri,
    const float* __restrict__ Dp,
    int L, int lognch)
{
    __shared__ float4 tlsv[1024];          // 256 slots * 4
    const int KEPT = 32 / DS;
    int tid = threadIdx.x;
    int nch = 1 << lognch;
    int sh  = tid & 1;
    int j   = (tid >> 1) & (nch - 1);
    int rpb = 128 >> lognch;
    int lr  = tid >> (1 + lognch);
    int row = blockIdx.x * rpb + lr;
    int b   = row / HDIM;
    int h   = row - b * HDIM;
    int c0  = j * 32;
    const float* ur = u + (size_t)row * L;
    int Lk = L / DS;

    float zr[8], zi[8], zCr[8], zCi[8], w0r[8], w0i[8], w1r[8], w1i[8];
    float dt = expf(log_dt[h]);
#pragma unroll
    for (int k = 0; k < 8; ++k) {
        int n = sh * 8 + k;
        float Ar = -expf(log_A_real[h * NSTATE + n]);
        float Ai = A_imag[h * NSTATE + n];
        float er = expf(dt * Ar);
        float th = dt * Ai;
        zr[k] = er * cosf(th); zi[k] = er * sinf(th);
        float pr = zr[k], pi = zi[k];          // zC = z^32 via 5 squarings
#pragma unroll
        for (int s = 0; s < 5; ++s) {
            float t2 = pr * pr - pi * pi;
            pi = 2.f * pr * pi; pr = t2;
        }
        zCr[k] = pr; zCi[k] = pi;
        float den = Ar * Ar + Ai * Ai;
        float t0 = zr[k] - 1.0f;
        float dBr = (t0 * Ar + zi[k] * Ai) / den;
        float dBi = (zi[k] * Ar - t0 * Ai) / den;
        float C0r = C_ri[((0 * HDIM + h) * NSTATE + n) * 2 + 0];
        float C0i = C_ri[((0 * HDIM + h) * NSTATE + n) * 2 + 1];
        float C1r = C_ri[((1 * HDIM + h) * NSTATE + n) * 2 + 0];
        float C1i = C_ri[((1 * HDIM + h) * NSTATE + n) * 2 + 1];
        w0r[k] = 2.0f * (C0r * dBr - C0i * dBi);
        w0i[k] = 2.0f * (C0r * dBi + C0i * dBr);
        w1r[k] = 2.0f * (C1r * dBr - C1i * dBi);
        w1i[k] = 2.0f * (C1r * dBi + C1i * dBr);
    }
    int myslot = (j * rpb + lr) * 2 + sh;

    // A1: forward local end-state
    {
        float sr_[8] = {}, si_[8] = {};
#pragma unroll 8
        for (int i = 0; i < 32; ++i) {
            float uf = ur[c0 + i];
#pragma unroll
            for (int k = 0; k < 8; ++k) {
                float nr = fmaf(zr[k], sr_[k], fmaf(-zi[k], si_[k], uf));
                si_[k] = fmaf(zr[k], si_[k], zi[k] * sr_[k]);
                sr_[k] = nr;
            }
        }
#pragma unroll
        for (int q = 0; q < 4; ++q)
            tlsv[myslot * 4 + (q ^ (myslot & 3))] =
                make_float4(sr_[2 * q], si_[2 * q], sr_[2 * q + 1], si_[2 * q + 1]);
    }
    __syncthreads();

    // B-fwd prefix
    float Sr[8] = {}, Si[8] = {};
    for (int i = 0; i < j; ++i) {
        int sl = (i * rpb + lr) * 2 + sh;
        float4 t0v = tlsv[sl * 4 + (0 ^ (sl & 3))];
        float4 t1v = tlsv[sl * 4 + (1 ^ (sl & 3))];
        float4 t2v = tlsv[sl * 4 + (2 ^ (sl & 3))];
        float4 t3v = tlsv[sl * 4 + (3 ^ (sl & 3))];
        float tr[8] = {t0v.x, t0v.z, t1v.x, t1v.z, t2v.x, t2v.z, t3v.x, t3v.z};
        float ti[8] = {t0v.y, t0v.w, t1v.y, t1v.w, t2v.y, t2v.w, t3v.y, t3v.w};
#pragma unroll
        for (int k = 0; k < 8; ++k) {
            float nr = fmaf(zCr[k], Sr[k], fmaf(-zCi[k], Si[k], tr[k]));
            Si[k] = fmaf(zCr[k], Si[k], fmaf(zCi[k], Sr[k], ti[k]));
            Sr[k] = nr;
        }
    }

    // C1: forward emit into registers
    float Dh_eff = (sh == 0) ? Dp[h] : 0.0f;
    float cf[KEPT];
#pragma unroll
    for (int i = 0; i < 32; ++i) {
        float uf = ur[c0 + i];
        float ca = 0.f, cb = 0.f;
#pragma unroll
        for (int k = 0; k < 8; ++k) {
            float nr = fmaf(zr[k], Sr[k], fmaf(-zi[k], Si[k], uf));
            Si[k] = fmaf(zr[k], Si[k], zi[k] * Sr[k]);
            Sr[k] = nr;
            float c = fmaf(w0r[k], Sr[k], -w0i[k] * Si[k]);
            if (k & 1) cb += c; else ca += c;
        }
        if ((i & (DS - 1)) == 0)
            cf[i / DS] = fmaf(Dh_eff, uf, ca + cb);
    }
    __syncthreads();

    // A2: backward local end-state
    {
        float sr_[8] = {}, si_[8] = {};
#pragma unroll 8
        for (int m = 0; m < 32; ++m) {
            int idx = c0 + 32 - m;
            float ub = (idx < L) ? ur[idx] : 0.f;
#pragma unroll
            for (int k = 0; k < 8; ++k) {
                float nr = fmaf(zr[k], sr_[k], fmaf(-zi[k], si_[k], ub));
                si_[k] = fmaf(zr[k], si_[k], zi[k] * sr_[k]);
                sr_[k] = nr;
            }
        }
#pragma unroll
        for (int q = 0; q < 4; ++q)
            tlsv[myslot * 4 + (q ^ (myslot & 3))] =
                make_float4(sr_[2 * q], si_[2 * q], sr_[2 * q + 1], si_[2 * q + 1]);
    }
    __syncthreads();

    // B-bwd suffix
    float Er[8] = {}, Ei[8] = {};
    for (int i = nch - 1; i > j; --i) {
        int sl = (i * rpb + lr) * 2 + sh;
        float4 t0v = tlsv[sl * 4 + (0 ^ (sl & 3))];
        float4 t1v = tlsv[sl * 4 + (1 ^ (sl & 3))];
        float4 t2v = tlsv[sl * 4 + (2 ^ (sl & 3))];
        float4 t3v = tlsv[sl * 4 + (3 ^ (sl & 3))];
        float tr[8] = {t0v.x, t0v.z, t1v.x, t1v.z, t2v.x, t2v.z, t3v.x, t3v.z};
        float ti[8] = {t0v.y, t0v.w, t1v.y, t1v.w, t2v.y, t2v.w, t3v.y, t3v.w};
#pragma unroll
        for (int k = 0; k < 8; ++k) {
            float nr = fmaf(zCr[k], Er[k], fmaf(-zCi[k], Ei[k], tr[k]));
            Ei[k] = fmaf(zCr[k], Ei[k], fmaf(zCi[k], Er[k], ti[k]));
            Er[k] = nr;
        }
    }

    // C2: backward emit, pair-sum via shfl, store f32 row-major
    float* yr = yout + (size_t)row * Lk + (c0 / DS);
#pragma unroll
    for (int m = 0; m < 32; ++m) {
        int idx = c0 + 32 - m;
        float ub = (idx < L) ? ur[idx] : 0.f;
#pragma unroll
        for (int k = 0; k < 8; ++k) {
            float nr = fmaf(zr[k], Er[k], fmaf(-zi[k], Ei[k], ub));
            Ei[k] = fmaf(zr[k], Ei[k], zi[k] * Er[k]);
            Er[k] = nr;
        }
        if (((31 - m) & (DS - 1)) == 0) {
            float ca = 0.f, cb = 0.f;
#pragma unroll
            for (int k = 0; k < 8; ++k) {
                float c = fmaf(w1r[k], Er[k], -w1i[k] * Ei[k]);
                if (k & 1) cb += c; else ca += c;
            }
            int k2 = (31 - m) / DS;
            float v = cf[k2] + ca + cb;
            v += __shfl_xor(v, 1, 64);
            if (sh == 0) {
                float g = 0.5f * v * (1.0f + erff(v * 0.70710678118f));
                yr[k2] = g;
            }
        }
    }
}

// ---------------------------------------------------------------------------
// ytr: transpose (6144 rows, Lk) f32 -> (B, Lk, 768) bf16, LDS-tiled 64x64
// ---------------------------------------------------------------------------
__global__ void __launch_bounds__(256) ytr_kernel(
    const float* __restrict__ yf, unsigned short* __restrict__ yt, int Lk)
{
    __shared__ float tile[64][65];
    int tid = threadIdx.x;
    int p0 = blockIdx.x * 64;
    int r0 = blockIdx.y * 64;
    int tp = tid & 63, th = tid >> 6;
#pragma unroll
    for (int s = 0; s < 16; ++s) {
        int hh = th * 16 + s;
        tile[hh][tp] = yf[(size_t)(r0 + hh) * Lk + p0 + tp];
    }
    __syncthreads();
    int b = r0 / HDIM, h0 = r0 - b * HDIM;
#pragma unroll
    for (int s = 0; s < 16; ++s) {
        int pp = th * 16 + s;
        yt[((size_t)b * Lk + p0 + pp) * HDIM + h0 + tp] = f2bf(tile[tp][pp]);
    }
}

// ---------------------------------------------------------------------------
// LayerNorm over H of (B, H, Lk)
// ---------------------------------------------------------------------------
__global__ void __launch_bounds__(256) ln_kernel(
    const float* __restrict__ x, float* __restrict__ dst,
    const float* __restrict__ nw, const float* __restrict__ nb, int Lk)
{
    __shared__ float ss[16][17], qq[16][17], mus[16], rss[16];
    int tid = threadIdx.x;
    int lo = tid & 15, hg = tid >> 4;
    int b = blockIdx.y;
    int l = blockIdx.x * 16 + lo;
    const float* base = x + (size_t)b * HDIM * Lk + l;
    float s = 0.f, q = 0.f;
    for (int hh = hg; hh < HDIM; hh += 16) {
        float v = base[(size_t)hh * Lk];
        s += v; q = fmaf(v, v, q);
    }
    ss[hg][lo] = s; qq[hg][lo] = q;
    __syncthreads();
    if (hg == 0) {
        float S = 0.f, Q = 0.f;
#pragma unroll
        for (int t2 = 0; t2 < 16; ++t2) { S += ss[t2][lo]; Q += qq[t2][lo]; }
        float mu = S * (1.0f / HDIM);
        float var = Q * (1.0f / HDIM) - mu * mu;
        mus[lo] = mu; rss[lo] = rsqrtf(var + 1e-5f);
    }
    __syncthreads();
    float mu = mus[lo], rs = rss[lo];
    float* dbase = dst + (size_t)b * HDIM * Lk + l;
    for (int hh = hg; hh < HDIM; hh += 16) {
        float v = base[(size_t)hh * Lk];
        dbase[(size_t)hh * Lk] = (v - mu) * rs * nw[hh] + nb[hh];
    }
}

// ---------------------------------------------------------------------------
// Head: out[b,l,o] = sum_h u[b,h,l]*wout[h,o] + wb[o]  (f32)
// LDS-staged u tile (64h x 64l) with 4 independent float4 loads/thread/tile
// to hide L2 latency (was: 768 wave-serial line loads -> 306 us).
// ---------------------------------------------------------------------------
__global__ void __launch_bounds__(256) head_kernel(
    const float* __restrict__ u, const float* __restrict__ wout,
    const float* __restrict__ wb, float* __restrict__ out, int Lk)
{
    __shared__ float us[64][68];     // [hh][l], +4 pad keeps float4 alignment
    __shared__ float wsh[64][40];
    int tid = threadIdx.x;
    int lt = tid & 63, og = tid >> 6;
    int b = blockIdx.y;
    int l0 = blockIdx.x * 64;
    int ur_ = tid >> 2, uq = tid & 3;          // staging: row, quad-group
    float acc[10];
#pragma unroll
    for (int k = 0; k < 10; ++k) acc[k] = 0.f;

    for (int c0 = 0; c0 < HDIM; c0 += 64) {
        // stage weights (64h x 38o)
        for (int p = tid; p < 64 * 38; p += 256) {
            int hh = p / 38, o = p - hh * 38;
            wsh[hh][o] = wout[(size_t)(c0 + hh) * 38 + o];
        }
        // stage u tile: thread -> row ur_, float4s uq, uq+4, uq+8, uq+12 (independent)
        {
            const float* gr = u + ((size_t)b * HDIM + c0 + ur_) * Lk + l0;
            float4 v0 = *(const float4*)(gr + (uq + 0) * 4);
            float4 v1 = *(const float4*)(gr + (uq + 4) * 4);
            float4 v2 = *(const float4*)(gr + (uq + 8) * 4);
            float4 v3 = *(const float4*)(gr + (uq + 12) * 4);
            *(float4*)&us[ur_][(uq + 0) * 4] = v0;
            *(float4*)&us[ur_][(uq + 4) * 4] = v1;
            *(float4*)&us[ur_][(uq + 8) * 4] = v2;
            *(float4*)&us[ur_][(uq + 12) * 4] = v3;
        }
        __syncthreads();
#pragma unroll 8
        for (int hh = 0; hh < 64; ++hh) {
            float uv = us[hh][lt];
#pragma unroll
            for (int k = 0; k < 10; ++k) {
                int o = og + 4 * k;
                if (o < 38) acc[k] = fmaf(uv, wsh[hh][o], acc[k]);
            }
        }
        __syncthreads();
    }
#pragma unroll
    for (int k = 0; k < 10; ++k) {
        int o = og + 4 * k;
        if (o < 38)
            out[((size_t)b * Lk + l0 + lt) * 38 + o] = acc[k] + wb[o];
    }
}

// ---------------------------------------------------------------------------
extern "C" void kernel_launch(void* const* d_in, const int* in_sizes, int n_in,
                              void* d_out, int out_size, void* d_ws, size_t ws_size,
                              hipStream_t stream)
{
    (void)in_sizes; (void)n_in; (void)out_size; (void)ws_size;
    const float* x_raw      = (const float*)d_in[1];
    const float* enc_w1     = (const float*)d_in[3];
    const float* enc_b1     = (const float*)d_in[4];
    const float* enc_w2     = (const float*)d_in[5];
    const float* enc_b2     = (const float*)d_in[6];
    const float* log_dt     = (const float*)d_in[7];
    const float* log_A_real = (const float*)d_in[8];
    const float* A_imag     = (const float*)d_in[9];
    const float* C_ri       = (const float*)d_in[10];
    const float* Dp         = (const float*)d_in[11];
    const float* out_w      = (const float*)d_in[12];
    const float* out_b      = (const float*)d_in[13];
    const float* norm_w     = (const float*)d_in[14];
    const float* norm_b     = (const float*)d_in[15];
    const float* wout_w     = (const float*)d_in[16];
    const float* wout_b     = (const float*)d_in[17];

    char* ws = (char*)d_ws;
    float* Abuf = (float*)ws;
    char*  Bb   = ws + 50331648;
    unsigned short* hbf   = (unsigned short*)Bb;
    unsigned short* ytb   = (unsigned short*)Bb;
    unsigned short* wslot = (unsigned short*)(Bb + 12582912);
    char*  Cb   = ws + 75497472;
    unsigned short* w2t = (unsigned short*)Cb;
    float* yf = (float*)Cb;
    float* xr = (float*)Cb;

    const int B = 8;

    w2t_kernel<<<288, 256, 0, stream>>>(enc_w2, w2t);
    hprep_kernel<<<6144, 256, 0, stream>>>(x_raw, enc_w1, enc_b1, hbf);
    enc_mfma_kernel<<<dim3(12, 128), 256, 0, stream>>>(w2t, hbf, enc_b2, Abuf);

    int L = 2048;
    for (int i = 0; i < 6; ++i) {
        int ds = (i <= 2) ? 2 : 1;
        int Lk = L / ds;
        int lognch = 31 - __builtin_clz(L / 32);     // chunks of 32
        int rpb = 128 >> lognch;
        int nblk = 6144 / rpb;
        if (ds == 2)
            ssm_split_kernel<2><<<nblk, 256, 0, stream>>>(
                Abuf, yf,
                log_dt + (size_t)i * HDIM,
                log_A_real + (size_t)i * HDIM * NSTATE,
                A_imag + (size_t)i * HDIM * NSTATE,
                C_ri + (size_t)i * 2 * HDIM * NSTATE * 2,
                Dp + (size_t)i * HDIM, L, lognch);
        else
            ssm_split_kernel<1><<<nblk, 256, 0, stream>>>(
                Abuf, yf,
                log_dt + (size_t)i * HDIM,
                log_A_real + (size_t)i * HDIM * NSTATE,
                A_imag + (size_t)i * HDIM * NSTATE,
                C_ri + (size_t)i * 2 * HDIM * NSTATE * 2,
                Dp + (size_t)i * HDIM, L, lognch);
        ytr_kernel<<<dim3(Lk / 64, 96), 256, 0, stream>>>(yf, ytb, Lk);
        wconv_kernel<<<576, 256, 0, stream>>>(
            out_w + (size_t)i * 1536 * HDIM, wslot, 1536 * 96);
        glu_mfma_kernel<<<dim3(12, Lk / 128, B), 256, 0, stream>>>(
            wslot, ytb, Abuf, out_b + (size_t)i * 1536, xr, Lk, ds);
        ln_kernel<<<dim3(Lk / 16, B), 256, 0, stream>>>(
            xr, Abuf, norm_w + (size_t)i * HDIM, norm_b + (size_t)i * HDIM, Lk);
        L = Lk;
    }

    head_kernel<<<dim3(L / 64, B), 256, 0, stream>>>(
        Abuf, wout_w, wout_b, (float*)d_out, L);
}

// Round 10
// 1196.163 us; speedup vs baseline: 3.0747x; 1.0392x over previous
//
#include <hip/hip_runtime.h>
#include <hip/hip_bf16.h>
#include <math.h>

#define HDIM 768
#define NSTATE 16

typedef __attribute__((ext_vector_type(8))) short bf16x8;
typedef __attribute__((ext_vector_type(4))) float f32x4;
typedef __attribute__((ext_vector_type(4))) unsigned int u32x4;

__device__ __forceinline__ unsigned short f2bf(float f) {
    union { float f; unsigned int u; } v; v.f = f;
    unsigned int r = v.u + 0x7fff + ((v.u >> 16) & 1);   // RNE
    return (unsigned short)(r >> 16);
}

// ---------------------------------------------------------------------------
// wconv: f32 -> bf16 flat copy (8 elems/thread)
// ---------------------------------------------------------------------------
__global__ void __launch_bounds__(256) wconv_kernel(
    const float* __restrict__ src, unsigned short* __restrict__ dst, int n8)
{
    int t = blockIdx.x * 256 + threadIdx.x;
    if (t >= n8) return;
    const float* s = src + (size_t)t * 8;
    float4 a = *(const float4*)s, b = *(const float4*)(s + 4);
    union { unsigned short us[8]; u32x4 v; } o;
    o.us[0] = f2bf(a.x); o.us[1] = f2bf(a.y); o.us[2] = f2bf(a.z); o.us[3] = f2bf(a.w);
    o.us[4] = f2bf(b.x); o.us[5] = f2bf(b.y); o.us[6] = f2bf(b.z); o.us[7] = f2bf(b.w);
    *(u32x4*)(dst + (size_t)t * 8) = o.v;
}

// ---------------------------------------------------------------------------
// w2t: transpose + convert enc_w2 (768k x 768j) -> (768j x 768k) bf16
// ---------------------------------------------------------------------------
__global__ void __launch_bounds__(256) w2t_kernel(
    const float* __restrict__ w2, unsigned short* __restrict__ w2t)
{
    int T = blockIdx.x * 256 + threadIdx.x;   // < 768*96
    int j = T / 96, kc = T - j * 96;
    union { unsigned short us[8]; u32x4 v; } o;
#pragma unroll
    for (int i = 0; i < 8; ++i)
        o.us[i] = f2bf(w2[(size_t)(kc * 8 + i) * HDIM + j]);
    *(u32x4*)(w2t + (size_t)j * HDIM + kc * 8) = o.v;
}

// ---------------------------------------------------------------------------
// hprep: h[r][k] = softsign(x_raw[r] @ w1[:,k] + b1[k]) -> bf16 (16384, 768)
// ---------------------------------------------------------------------------
__global__ void __launch_bounds__(256) hprep_kernel(
    const float* __restrict__ xraw, const float* __restrict__ w1,
    const float* __restrict__ b1, unsigned short* __restrict__ hbf)
{
    __shared__ float w1s[8 * HDIM];
    __shared__ float b1s[HDIM];
    int tid = threadIdx.x;
    for (int p = tid; p < 8 * HDIM; p += 256) w1s[p] = w1[p];
    for (int p = tid; p < HDIM; p += 256) b1s[p] = b1[p];
    __syncthreads();
    int T = blockIdx.x * 256 + tid;           // < 16384*96
    int r = T / 96, kc = T - r * 96;
    float4 xa = *(const float4*)(xraw + (size_t)r * 8);
    float4 xb = *(const float4*)(xraw + (size_t)r * 8 + 4);
    float xq[8] = {xa.x, xa.y, xa.z, xa.w, xb.x, xb.y, xb.z, xb.w};
    float acc[8];
#pragma unroll
    for (int i = 0; i < 8; ++i) acc[i] = b1s[kc * 8 + i];
#pragma unroll
    for (int q = 0; q < 8; ++q)
#pragma unroll
        for (int i = 0; i < 8; ++i)
            acc[i] = fmaf(xq[q], w1s[q * HDIM + kc * 8 + i], acc[i]);
    union { unsigned short us[8]; u32x4 v; } o;
#pragma unroll
    for (int i = 0; i < 8; ++i) {
        float h = acc[i] / (1.0f + fabsf(acc[i]));
        o.us[i] = f2bf(h);
    }
    *(u32x4*)(hbf + (size_t)r * HDIM + kc * 8) = o.v;
}

// ---------------------------------------------------------------------------
// enc_mfma: u0 (B,768,2048) f32 = w2t(768j,768k) @ hbf(16384r,768k)^T + b2
// ---------------------------------------------------------------------------
__global__ void __launch_bounds__(256) enc_mfma_kernel(
    const unsigned short* __restrict__ w2t,
    const unsigned short* __restrict__ hbf,
    const float* __restrict__ b2,
    float* __restrict__ u0)
{
    __shared__ unsigned short lds[2][192 * 64];
    int tid = threadIdx.x;
    int j0 = blockIdx.x * 64;
    int r0 = blockIdx.y * 128;
    int w = tid >> 6, lane = tid & 63;
    int wj = w >> 1, wl = w & 1;
    f32x4 acc[2][4];
    f32x4 zf = {0.f, 0.f, 0.f, 0.f};
#pragma unroll
    for (int dg = 0; dg < 2; ++dg)
#pragma unroll
        for (int cg = 0; cg < 4; ++cg) acc[dg][cg] = zf;

    u32x4 stg[6];
#define ENC_LOAD(kt) do { int k0_ = (kt) * 64; \
    _Pragma("unroll") for (int s = 0; s < 6; ++s) { \
        int c = s * 256 + tid; int row = c >> 3, m = c & 7; \
        const unsigned short* g = (row < 64) \
            ? (w2t + (size_t)(j0 + row) * HDIM + k0_ + m * 8) \
            : (hbf + (size_t)(r0 + row - 64) * HDIM + k0_ + m * 8); \
        stg[s] = *(const u32x4*)g; } } while (0)
#define ENC_WRITE(bi) do { \
    _Pragma("unroll") for (int s = 0; s < 6; ++s) { \
        int c = s * 256 + tid; int row = c >> 3, m = c & 7; \
        *(u32x4*)&lds[bi][row * 64 + 8 * (m ^ (row & 7))] = stg[s]; } } while (0)

    ENC_LOAD(0); ENC_WRITE(0);
    int cur = 0;
    for (int t = 0; t < 12; ++t) {
        __syncthreads();
        if (t < 11) ENC_LOAD(t + 1);
#pragma unroll
        for (int kh = 0; kh < 2; ++kh) {
            int kg = kh * 4 + (lane >> 4);
            bf16x8 af[2], bfr[4];
#pragma unroll
            for (int dg = 0; dg < 2; ++dg) {
                int rA = wj * 32 + dg * 16 + (lane & 15);
                af[dg] = *(bf16x8*)&lds[cur][rA * 64 + 8 * (kg ^ (rA & 7))];
            }
#pragma unroll
            for (int cg = 0; cg < 4; ++cg) {
                int rB = 64 + wl * 64 + cg * 16 + (lane & 15);
                bfr[cg] = *(bf16x8*)&lds[cur][rB * 64 + 8 * (kg ^ (rB & 7))];
            }
#pragma unroll
            for (int dg = 0; dg < 2; ++dg)
#pragma unroll
                for (int cg = 0; cg < 4; ++cg)
                    acc[dg][cg] = __builtin_amdgcn_mfma_f32_16x16x32_bf16(
                        af[dg], bfr[cg], acc[dg][cg], 0, 0, 0);
        }
        if (t < 11) ENC_WRITE(cur ^ 1);
        cur ^= 1;
    }
    int b = r0 >> 11;
    int l0 = r0 & 2047;
#pragma unroll
    for (int dg = 0; dg < 2; ++dg) {
        int j = j0 + wj * 32 + dg * 16 + ((lane >> 4) << 2);
#pragma unroll
        for (int cg = 0; cg < 4; ++cg) {
            int l = l0 + wl * 64 + cg * 16 + (lane & 15);
#pragma unroll
            for (int i = 0; i < 4; ++i)
                u0[((size_t)(b * HDIM + j + i)) * 2048 + l] = acc[dg][cg][i] + b2[j + i];
        }
    }
#undef ENC_LOAD
#undef ENC_WRITE
}

// ---------------------------------------------------------------------------
// glu_mfma: a = W[0:768]@Y, g = W[768:]@Y (bf16 MFMA, f32 acc);
//           xr = (a+ba)*sigmoid(g+bg) + u[:, ::ds]   out (B,768,Lk) f32
// ---------------------------------------------------------------------------
__global__ void __launch_bounds__(256) glu_mfma_kernel(
    const unsigned short* __restrict__ wbf,   // (1536, 768) bf16
    const unsigned short* __restrict__ yt,    // (B, Lk, 768) bf16
    const float* __restrict__ u,              // (B, 768, Lk*ds)
    const float* __restrict__ ob,             // (1536)
    float* __restrict__ xr,                   // (B, 768, Lk)
    int Lk, int ds)
{
    __shared__ unsigned short lds[2][256 * 64];
    int tid = threadIdx.x;
    int d0 = blockIdx.x * 64;
    int l0 = blockIdx.y * 128;
    int b  = blockIdx.z;
    int w = tid >> 6, lane = tid & 63;
    int wd = w >> 1, wl = w & 1;
    f32x4 accA[2][4], accG[2][4];
    f32x4 zf = {0.f, 0.f, 0.f, 0.f};
#pragma unroll
    for (int dg = 0; dg < 2; ++dg)
#pragma unroll
        for (int cg = 0; cg < 4; ++cg) { accA[dg][cg] = zf; accG[dg][cg] = zf; }

    u32x4 stg[8];
#define GLU_LOAD(kt) do { int k0_ = (kt) * 64; \
    _Pragma("unroll") for (int s = 0; s < 8; ++s) { \
        int c = s * 256 + tid; int row = c >> 3, m = c & 7; \
        const unsigned short* g; \
        if (row < 64)       g = wbf + (size_t)(d0 + row) * HDIM + k0_ + m * 8; \
        else if (row < 128) g = wbf + (size_t)(768 + d0 + row - 64) * HDIM + k0_ + m * 8; \
        else g = yt + ((size_t)b * Lk + l0 + row - 128) * HDIM + k0_ + m * 8; \
        stg[s] = *(const u32x4*)g; } } while (0)
#define GLU_WRITE(bi) do { \
    _Pragma("unroll") for (int s = 0; s < 8; ++s) { \
        int c = s * 256 + tid; int row = c >> 3, m = c & 7; \
        *(u32x4*)&lds[bi][row * 64 + 8 * (m ^ (row & 7))] = stg[s]; } } while (0)

    GLU_LOAD(0); GLU_WRITE(0);
    int cur = 0;
    for (int t = 0; t < 12; ++t) {
        __syncthreads();
        if (t < 11) GLU_LOAD(t + 1);
#pragma unroll
        for (int kh = 0; kh < 2; ++kh) {
            int kg = kh * 4 + (lane >> 4);
            bf16x8 aa[2], ag[2], bfr[4];
#pragma unroll
            for (int dg = 0; dg < 2; ++dg) {
                int rA = wd * 32 + dg * 16 + (lane & 15);
                aa[dg] = *(bf16x8*)&lds[cur][rA * 64 + 8 * (kg ^ (rA & 7))];
                int rG = 64 + rA;
                ag[dg] = *(bf16x8*)&lds[cur][rG * 64 + 8 * (kg ^ (rG & 7))];
            }
#pragma unroll
            for (int cg = 0; cg < 4; ++cg) {
                int rB = 128 + wl * 64 + cg * 16 + (lane & 15);
                bfr[cg] = *(bf16x8*)&lds[cur][rB * 64 + 8 * (kg ^ (rB & 7))];
            }
#pragma unroll
            for (int dg = 0; dg < 2; ++dg)
#pragma unroll
                for (int cg = 0; cg < 4; ++cg) {
                    accA[dg][cg] = __builtin_amdgcn_mfma_f32_16x16x32_bf16(
                        aa[dg], bfr[cg], accA[dg][cg], 0, 0, 0);
                    accG[dg][cg] = __builtin_amdgcn_mfma_f32_16x16x32_bf16(
                        ag[dg], bfr[cg], accG[dg][cg], 0, 0, 0);
                }
        }
        if (t < 11) GLU_WRITE(cur ^ 1);
        cur ^= 1;
    }
    size_t L = (size_t)Lk * ds;
#pragma unroll
    for (int dg = 0; dg < 2; ++dg) {
        int d = d0 + wd * 32 + dg * 16 + ((lane >> 4) << 2);
#pragma unroll
        for (int cg = 0; cg < 4; ++cg) {
            int l = l0 + wl * 64 + cg * 16 + (lane & 15);
#pragma unroll
            for (int i = 0; i < 4; ++i) {
                float a = accA[dg][cg][i] + ob[d + i];
                float g = accG[dg][cg][i] + ob[d + i + 768];
                float sg = 1.0f / (1.0f + expf(-g));
                float res = u[((size_t)b * HDIM + d + i) * L + (size_t)l * ds];
                xr[((size_t)b * HDIM + d + i) * Lk + l] = fmaf(a, sg, res);
            }
        }
    }
#undef GLU_LOAD
#undef GLU_WRITE
}

// ---------------------------------------------------------------------------
// SSM, chunk-parallel, 2-way state split, CHUNK=32, with KOGGE-STONE scan
// over chunks (replaces serial per-thread combine; removes wave divergence).
// Scan op: P_j = zC*P_{j-1} + T_j  (uniform multiplier zC^(2^k) per step).
// S_j = P_{j-1} (fwd);  E_j = Q_{j+1} with reverse scan (bwd).
// ---------------------------------------------------------------------------
template<int DS>
__global__ void __launch_bounds__(256) ssm_scan_kernel(
    const float* __restrict__ u,          // (6144, L)
    float* __restrict__ yout,             // (6144, L/DS) f32, gelu'd
    const float* __restrict__ log_dt,
    const float* __restrict__ log_A_real,
    const float* __restrict__ A_imag,
    const float* __restrict__ C_ri,
    const float* __restrict__ Dp,
    int L, int lognch)
{
    __shared__ float4 tlsv[1024];          // 256 slots * 4
    const int KEPT = 32 / DS;
    int tid = threadIdx.x;
    int nch = 1 << lognch;
    int sh  = tid & 1;
    int j   = (tid >> 1) & (nch - 1);
    int rpb = 128 >> lognch;
    int lr  = tid >> (1 + lognch);
    int row = blockIdx.x * rpb + lr;
    int b   = row / HDIM;
    int h   = row - b * HDIM;
    int c0  = j * 32;
    const float* ur = u + (size_t)row * L;
    int Lk = L / DS;

    float zr[8], zi[8], zCr[8], zCi[8], w0r[8], w0i[8], w1r[8], w1i[8];
    float dt = expf(log_dt[h]);
#pragma unroll
    for (int k = 0; k < 8; ++k) {
        int n = sh * 8 + k;
        float Ar = -expf(log_A_real[h * NSTATE + n]);
        float Ai = A_imag[h * NSTATE + n];
        float er = expf(dt * Ar);
        float th = dt * Ai;
        zr[k] = er * cosf(th); zi[k] = er * sinf(th);
        float pr = zr[k], pi = zi[k];          // zC = z^32 via 5 squarings
#pragma unroll
        for (int s = 0; s < 5; ++s) {
            float t2 = pr * pr - pi * pi;
            pi = 2.f * pr * pi; pr = t2;
        }
        zCr[k] = pr; zCi[k] = pi;
        float den = Ar * Ar + Ai * Ai;
        float t0 = zr[k] - 1.0f;
        float dBr = (t0 * Ar + zi[k] * Ai) / den;
        float dBi = (zi[k] * Ar - t0 * Ai) / den;
        float C0r = C_ri[((0 * HDIM + h) * NSTATE + n) * 2 + 0];
        float C0i = C_ri[((0 * HDIM + h) * NSTATE + n) * 2 + 1];
        float C1r = C_ri[((1 * HDIM + h) * NSTATE + n) * 2 + 0];
        float C1i = C_ri[((1 * HDIM + h) * NSTATE + n) * 2 + 1];
        w0r[k] = 2.0f * (C0r * dBr - C0i * dBi);
        w0i[k] = 2.0f * (C0r * dBi + C0i * dBr);
        w1r[k] = 2.0f * (C1r * dBr - C1i * dBi);
        w1i[k] = 2.0f * (C1r * dBi + C1i * dBr);
    }
    int myslot = (j * rpb + lr) * 2 + sh;

#define SLOT_WRITE(RR, II) do { \
    _Pragma("unroll") for (int q = 0; q < 4; ++q) \
        tlsv[myslot * 4 + (q ^ (myslot & 3))] = \
            make_float4(RR[2 * q], II[2 * q], RR[2 * q + 1], II[2 * q + 1]); } while (0)
#define SLOT_READ(SL, RR, II) do { int sl_ = (SL); \
    float4 a0 = tlsv[sl_ * 4 + (0 ^ (sl_ & 3))]; \
    float4 a1 = tlsv[sl_ * 4 + (1 ^ (sl_ & 3))]; \
    float4 a2 = tlsv[sl_ * 4 + (2 ^ (sl_ & 3))]; \
    float4 a3 = tlsv[sl_ * 4 + (3 ^ (sl_ & 3))]; \
    RR[0] = a0.x; II[0] = a0.y; RR[1] = a0.z; II[1] = a0.w; \
    RR[2] = a1.x; II[2] = a1.y; RR[3] = a1.z; II[3] = a1.w; \
    RR[4] = a2.x; II[4] = a2.y; RR[5] = a2.z; II[5] = a2.w; \
    RR[6] = a3.x; II[6] = a3.y; RR[7] = a3.z; II[7] = a3.w; } while (0)

    float Pr[8], Pi[8];
    // A1: forward local scan (zero init) -> P^0 = T_j
    {
        float sr_[8] = {}, si_[8] = {};
#pragma unroll 8
        for (int i = 0; i < 32; ++i) {
            float uf = ur[c0 + i];
#pragma unroll
            for (int k = 0; k < 8; ++k) {
                float nr = fmaf(zr[k], sr_[k], fmaf(-zi[k], si_[k], uf));
                si_[k] = fmaf(zr[k], si_[k], zi[k] * sr_[k]);
                sr_[k] = nr;
            }
        }
#pragma unroll
        for (int k = 0; k < 8; ++k) { Pr[k] = sr_[k]; Pi[k] = si_[k]; }
    }
    SLOT_WRITE(Pr, Pi);
    __syncthreads();

    // fwd Kogge-Stone: P_j = sum_{i<=j} zC^(j-i) T_i
    {
        float wkr[8], wki[8];
#pragma unroll
        for (int k = 0; k < 8; ++k) { wkr[k] = zCr[k]; wki[k] = zCi[k]; }
        for (int st = 0; st < lognch; ++st) {
            int pj = j - (1 << st);
            float tr[8], ti[8];
            bool act = (pj >= 0);
            if (act) SLOT_READ((pj * rpb + lr) * 2 + sh, tr, ti);
            __syncthreads();
            if (act) {
#pragma unroll
                for (int k = 0; k < 8; ++k) {
                    Pr[k] = fmaf(wkr[k], tr[k], fmaf(-wki[k], ti[k], Pr[k]));
                    Pi[k] = fmaf(wkr[k], ti[k], fmaf(wki[k], tr[k], Pi[k]));
                }
            }
            SLOT_WRITE(Pr, Pi);
            __syncthreads();
#pragma unroll
            for (int k = 0; k < 8; ++k) {
                float t2 = wkr[k] * wkr[k] - wki[k] * wki[k];
                wki[k] = 2.f * wkr[k] * wki[k]; wkr[k] = t2;
            }
        }
    }
    // S_j = P_{j-1}
    float Sr[8] = {}, Si[8] = {};
    if (j > 0) SLOT_READ(((j - 1) * rpb + lr) * 2 + sh, Sr, Si);

    // C1: forward emit into registers (emission only at kept positions)
    float Dh_eff = (sh == 0) ? Dp[h] : 0.0f;
    float cf[KEPT];
#pragma unroll
    for (int i = 0; i < 32; ++i) {
        float uf = ur[c0 + i];
#pragma unroll
        for (int k = 0; k < 8; ++k) {
            float nr = fmaf(zr[k], Sr[k], fmaf(-zi[k], Si[k], uf));
            Si[k] = fmaf(zr[k], Si[k], zi[k] * Sr[k]);
            Sr[k] = nr;
        }
        if ((i & (DS - 1)) == 0) {
            float ca = 0.f, cb = 0.f;
#pragma unroll
            for (int k = 0; k < 8; ++k) {
                float c = fmaf(w0r[k], Sr[k], -w0i[k] * Si[k]);
                if (k & 1) cb += c; else ca += c;
            }
            cf[i / DS] = fmaf(Dh_eff, uf, ca + cb);
        }
    }
    __syncthreads();   // all scan reads complete before LDS reuse

    // A2: backward local scan -> Q^0 = Tb_j
    {
        float sr_[8] = {}, si_[8] = {};
#pragma unroll 8
        for (int m = 0; m < 32; ++m) {
            int idx = c0 + 32 - m;
            float ub = (idx < L) ? ur[idx] : 0.f;
#pragma unroll
            for (int k = 0; k < 8; ++k) {
                float nr = fmaf(zr[k], sr_[k], fmaf(-zi[k], si_[k], ub));
                si_[k] = fmaf(zr[k], si_[k], zi[k] * sr_[k]);
                sr_[k] = nr;
            }
        }
#pragma unroll
        for (int k = 0; k < 8; ++k) { Pr[k] = sr_[k]; Pi[k] = si_[k]; }
    }
    SLOT_WRITE(Pr, Pi);
    __syncthreads();

    // bwd Kogge-Stone: Q_j = sum_{i>=j} zC^(i-j) Tb_i
    {
        float wkr[8], wki[8];
#pragma unroll
        for (int k = 0; k < 8; ++k) { wkr[k] = zCr[k]; wki[k] = zCi[k]; }
        for (int st = 0; st < lognch; ++st) {
            int pj = j + (1 << st);
            float tr[8], ti[8];
            bool act = (pj < nch);
            if (act) SLOT_READ((pj * rpb + lr) * 2 + sh, tr, ti);
            __syncthreads();
            if (act) {
#pragma unroll
                for (int k = 0; k < 8; ++k) {
                    Pr[k] = fmaf(wkr[k], tr[k], fmaf(-wki[k], ti[k], Pr[k]));
                    Pi[k] = fmaf(wkr[k], ti[k], fmaf(wki[k], tr[k], Pi[k]));
                }
            }
            SLOT_WRITE(Pr, Pi);
            __syncthreads();
#pragma unroll
            for (int k = 0; k < 8; ++k) {
                float t2 = wkr[k] * wkr[k] - wki[k] * wki[k];
                wki[k] = 2.f * wkr[k] * wki[k]; wkr[k] = t2;
            }
        }
    }
    // E_j = Q_{j+1}
    float Er[8] = {}, Ei[8] = {};
    if (j < nch - 1) SLOT_READ(((j + 1) * rpb + lr) * 2 + sh, Er, Ei);

    // C2: backward emit, pair-sum via shfl, store f32 row-major
    float* yr = yout + (size_t)row * Lk + (c0 / DS);
#pragma unroll
    for (int m = 0; m < 32; ++m) {
        int idx = c0 + 32 - m;
        float ub = (idx < L) ? ur[idx] : 0.f;
#pragma unroll
        for (int k = 0; k < 8; ++k) {
            float nr = fmaf(zr[k], Er[k], fmaf(-zi[k], Ei[k], ub));
            Ei[k] = fmaf(zr[k], Ei[k], zi[k] * Er[k]);
            Er[k] = nr;
        }
        if (((31 - m) & (DS - 1)) == 0) {
            float ca = 0.f, cb = 0.f;
#pragma unroll
            for (int k = 0; k < 8; ++k) {
                float c = fmaf(w1r[k], Er[k], -w1i[k] * Ei[k]);
                if (k & 1) cb += c; else ca += c;
            }
            int k2 = (31 - m) / DS;
            float v = cf[k2] + ca + cb;
            v += __shfl_xor(v, 1, 64);
            if (sh == 0) {
                float g = 0.5f * v * (1.0f + erff(v * 0.70710678118f));
                yr[k2] = g;
            }
        }
    }
#undef SLOT_WRITE
#undef SLOT_READ
}

// ---------------------------------------------------------------------------
// ytr: transpose (6144 rows, Lk) f32 -> (B, Lk, 768) bf16, LDS-tiled 64x64
// ---------------------------------------------------------------------------
__global__ void __launch_bounds__(256) ytr_kernel(
    const float* __restrict__ yf, unsigned short* __restrict__ yt, int Lk)
{
    __shared__ float tile[64][65];
    int tid = threadIdx.x;
    int p0 = blockIdx.x * 64;
    int r0 = blockIdx.y * 64;
    int tp = tid & 63, th = tid >> 6;
#pragma unroll
    for (int s = 0; s < 16; ++s) {
        int hh = th * 16 + s;
        tile[hh][tp] = yf[(size_t)(r0 + hh) * Lk + p0 + tp];
    }
    __syncthreads();
    int b = r0 / HDIM, h0 = r0 - b * HDIM;
#pragma unroll
    for (int s = 0; s < 16; ++s) {
        int pp = th * 16 + s;
        yt[((size_t)b * Lk + p0 + pp) * HDIM + h0 + tp] = f2bf(tile[tp][pp]);
    }
}

// ---------------------------------------------------------------------------
// LayerNorm over H of (B, H, Lk)
// ---------------------------------------------------------------------------
__global__ void __launch_bounds__(256) ln_kernel(
    const float* __restrict__ x, float* __restrict__ dst,
    const float* __restrict__ nw, const float* __restrict__ nb, int Lk)
{
    __shared__ float ss[16][17], qq[16][17], mus[16], rss[16];
    int tid = threadIdx.x;
    int lo = tid & 15, hg = tid >> 4;
    int b = blockIdx.y;
    int l = blockIdx.x * 16 + lo;
    const float* base = x + (size_t)b * HDIM * Lk + l;
    float s = 0.f, q = 0.f;
    for (int hh = hg; hh < HDIM; hh += 16) {
        float v = base[(size_t)hh * Lk];
        s += v; q = fmaf(v, v, q);
    }
    ss[hg][lo] = s; qq[hg][lo] = q;
    __syncthreads();
    if (hg == 0) {
        float S = 0.f, Q = 0.f;
#pragma unroll
        for (int t2 = 0; t2 < 16; ++t2) { S += ss[t2][lo]; Q += qq[t2][lo]; }
        float mu = S * (1.0f / HDIM);
        float var = Q * (1.0f / HDIM) - mu * mu;
        mus[lo] = mu; rss[lo] = rsqrtf(var + 1e-5f);
    }
    __syncthreads();
    float mu = mus[lo], rs = rss[lo];
    float* dbase = dst + (size_t)b * HDIM * Lk + l;
    for (int hh = hg; hh < HDIM; hh += 16) {
        float v = base[(size_t)hh * Lk];
        dbase[(size_t)hh * Lk] = (v - mu) * rs * nw[hh] + nb[hh];
    }
}

// ---------------------------------------------------------------------------
// Head: out[b,l,o] = sum_h u[b,h,l]*wout[h,o] + wb[o]  (f32)
// LDS-staged u tile with 4 independent float4 loads/thread/tile.
// ---------------------------------------------------------------------------
__global__ void __launch_bounds__(256) head_kernel(
    const float* __restrict__ u, const float* __restrict__ wout,
    const float* __restrict__ wb, float* __restrict__ out, int Lk)
{
    __shared__ float us[64][68];
    __shared__ float wsh[64][40];
    int tid = threadIdx.x;
    int lt = tid & 63, og = tid >> 6;
    int b = blockIdx.y;
    int l0 = blockIdx.x * 64;
    int ur_ = tid >> 2, uq = tid & 3;
    float acc[10];
#pragma unroll
    for (int k = 0; k < 10; ++k) acc[k] = 0.f;

    for (int c0 = 0; c0 < HDIM; c0 += 64) {
        for (int p = tid; p < 64 * 38; p += 256) {
            int hh = p / 38, o = p - hh * 38;
            wsh[hh][o] = wout[(size_t)(c0 + hh) * 38 + o];
        }
        {
            const float* gr = u + ((size_t)b * HDIM + c0 + ur_) * Lk + l0;
            float4 v0 = *(const float4*)(gr + (uq + 0) * 4);
            float4 v1 = *(const float4*)(gr + (uq + 4) * 4);
            float4 v2 = *(const float4*)(gr + (uq + 8) * 4);
            float4 v3 = *(const float4*)(gr + (uq + 12) * 4);
            *(float4*)&us[ur_][(uq + 0) * 4] = v0;
            *(float4*)&us[ur_][(uq + 4) * 4] = v1;
            *(float4*)&us[ur_][(uq + 8) * 4] = v2;
            *(float4*)&us[ur_][(uq + 12) * 4] = v3;
        }
        __syncthreads();
#pragma unroll 8
        for (int hh = 0; hh < 64; ++hh) {
            float uv = us[hh][lt];
#pragma unroll
            for (int k = 0; k < 10; ++k) {
                int o = og + 4 * k;
                if (o < 38) acc[k] = fmaf(uv, wsh[hh][o], acc[k]);
            }
        }
        __syncthreads();
    }
#pragma unroll
    for (int k = 0; k < 10; ++k) {
        int o = og + 4 * k;
        if (o < 38)
            out[((size_t)b * Lk + l0 + lt) * 38 + o] = acc[k] + wb[o];
    }
}

// ---------------------------------------------------------------------------
extern "C" void kernel_launch(void* const* d_in, const int* in_sizes, int n_in,
                              void* d_out, int out_size, void* d_ws, size_t ws_size,
                              hipStream_t stream)
{
    (void)in_sizes; (void)n_in; (void)out_size; (void)ws_size;
    const float* x_raw      = (const float*)d_in[1];
    const float* enc_w1     = (const float*)d_in[3];
    const float* enc_b1     = (const float*)d_in[4];
    const float* enc_w2     = (const float*)d_in[5];
    const float* enc_b2     = (const float*)d_in[6];
    const float* log_dt     = (const float*)d_in[7];
    const float* log_A_real = (const float*)d_in[8];
    const float* A_imag     = (const float*)d_in[9];
    const float* C_ri       = (const float*)d_in[10];
    const float* Dp         = (const float*)d_in[11];
    const float* out_w      = (const float*)d_in[12];
    const float* out_b      = (const float*)d_in[13];
    const float* norm_w     = (const float*)d_in[14];
    const float* norm_b     = (const float*)d_in[15];
    const float* wout_w     = (const float*)d_in[16];
    const float* wout_b     = (const float*)d_in[17];

    char* ws = (char*)d_ws;
    float* Abuf = (float*)ws;
    char*  Bb   = ws + 50331648;
    unsigned short* hbf   = (unsigned short*)Bb;
    unsigned short* ytb   = (unsigned short*)Bb;
    unsigned short* wslot = (unsigned short*)(Bb + 12582912);
    char*  Cb   = ws + 75497472;
    unsigned short* w2t = (unsigned short*)Cb;
    float* yf = (float*)Cb;
    float* xr = (float*)Cb;

    const int B = 8;

    w2t_kernel<<<288, 256, 0, stream>>>(enc_w2, w2t);
    hprep_kernel<<<6144, 256, 0, stream>>>(x_raw, enc_w1, enc_b1, hbf);
    enc_mfma_kernel<<<dim3(12, 128), 256, 0, stream>>>(w2t, hbf, enc_b2, Abuf);

    int L = 2048;
    for (int i = 0; i < 6; ++i) {
        int ds = (i <= 2) ? 2 : 1;
        int Lk = L / ds;
        int lognch = 31 - __builtin_clz(L / 32);     // chunks of 32
        int rpb = 128 >> lognch;
        int nblk = 6144 / rpb;
        if (ds == 2)
            ssm_scan_kernel<2><<<nblk, 256, 0, stream>>>(
                Abuf, yf,
                log_dt + (size_t)i * HDIM,
                log_A_real + (size_t)i * HDIM * NSTATE,
                A_imag + (size_t)i * HDIM * NSTATE,
                C_ri + (size_t)i * 2 * HDIM * NSTATE * 2,
                Dp + (size_t)i * HDIM, L, lognch);
        else
            ssm_scan_kernel<1><<<nblk, 256, 0, stream>>>(
                Abuf, yf,
                log_dt + (size_t)i * HDIM,
                log_A_real + (size_t)i * HDIM * NSTATE,
                A_imag + (size_t)i * HDIM * NSTATE,
                C_ri + (size_t)i * 2 * HDIM * NSTATE * 2,
                Dp + (size_t)i * HDIM, L, lognch);
        ytr_kernel<<<dim3(Lk / 64, 96), 256, 0, stream>>>(yf, ytb, Lk);
        wconv_kernel<<<576, 256, 0, stream>>>(
            out_w + (size_t)i * 1536 * HDIM, wslot, 1536 * 96);
        glu_mfma_kernel<<<dim3(12, Lk / 128, B), 256, 0, stream>>>(
            wslot, ytb, Abuf, out_b + (size_t)i * 1536, xr, Lk, ds);
        ln_kernel<<<dim3(Lk / 16, B), 256, 0, stream>>>(
            xr, Abuf, norm_w + (size_t)i * HDIM, norm_b + (size_t)i * HDIM, Lk);
        L = Lk;
    }

    head_kernel<<<dim3(L / 64, B), 256, 0, stream>>>(
        Abuf, wout_w, wout_b, (float*)d_out, L);
}